// Round 9
// baseline (277.432 us; speedup 1.0000x reference)
//
#include <hip/hip_runtime.h>
#include <hip/hip_bf16.h>
#include <cstdint>
#include <cstddef>

// Problem constants (fixed shapes)
#define Bn   4
#define Sn   4096
#define Nn   16384
#define CSn  256
#define COn  128
#define CINn 384
#define MTOT 65536   // B*N

using short8 = short __attribute__((ext_vector_type(8)));
using f32x4  = float __attribute__((ext_vector_type(4)));
using f32x2  = float __attribute__((ext_vector_type(2)));

static __device__ __forceinline__ float bf2f(unsigned short u){
  unsigned int x = ((unsigned int)u) << 16;
  return __builtin_bit_cast(float, x);
}
static __device__ __forceinline__ unsigned short f2bf(float f){
  unsigned int x = __builtin_bit_cast(unsigned int, f);
  x += 0x7fffu + ((x >> 16) & 1u);   // RNE
  return (unsigned short)(x >> 16);
}

// ---------------- KNN ----------------
// branchy insert used only in tiny merges (sorted-triple inputs)
static __device__ __forceinline__ void top3_insert(float d, int s,
    float& d0, float& d1, float& d2, int& i0, int& i1, int& i2){
  if (d < d2){
    if (d < d1){
      d2 = d1; i2 = i1;
      if (d < d0){ d1 = d0; i1 = i0; d0 = d; i0 = s; }
      else       { d1 = d;  i1 = s; }
    } else { d2 = d; i2 = s; }
  }
}

// branch-free top3 maintenance (R6-verified): strict '<', ascending scan order
static __device__ __forceinline__ void top3_bf(float dd, int sidx,
    float& d0, float& d1, float& d2, int& i0, int& i1, int& i2){
  const bool c0 = dd < d0, c1 = dd < d1, c2 = dd < d2;
  const float od0 = d0, od1 = d1;
  d0 = fminf(dd, od0);
  d1 = __builtin_amdgcn_fmed3f(dd, od0, od1);
  d2 = __builtin_amdgcn_fmed3f(dd, od1, d2);
  i2 = c2 ? (c1 ? i1 : sidx) : i2;    // old i1
  i1 = c1 ? (c0 ? i0 : sidx) : i1;    // old i0
  i0 = c0 ? sidx : i0;
}

// 2048 blocks x 256 threads (4 waves), fully wave-independent (NO barriers).
// Block = 64 queries (lane = query) x one S-half; wave w scans slice
// [half*2048 + w*512, +512), split into chain A = first 256 and chain B =
// second 256 (A indices < B indices -> strict-'<' A-then-B merge preserves
// top_k tie-break). Keys staged per-wave into double-buffered LDS chunks of
// 64 pairs, two contiguous planes (R8-verified conflict-free):
//   plane0[i] = {xA, xB, yA, yB}   plane1[i] = {zA, zB, ssA, ssB}
// Scan reads are wave-uniform ds_read_b128 broadcast; distance math packed
// f32x2 (2 keys/op), per-component rounding bit-identical to scalar chain:
// fma(-2, dot, add(qq,ss)), dot = fma(z, fma(y, mul(x))).
// Each wave writes its top-3 partial to global PD/PI[slice][j][gq] (SoA,
// coalesced); knnmerge_kernel merges the 8 slices in ascending key order.
// Grid 2048 = 8 blocks/CU, LDS 16 KB -> 32 waves/CU occupancy target.
__global__ __launch_bounds__(256) void knn_kernel(
    const float* __restrict__ sxyz, const float* __restrict__ oxyz,
    float* __restrict__ PD, int* __restrict__ PI)
{
  __shared__ float4 cb[4][2][2][64];   // 16 KB: [wave][dbuf][plane][pair]

  const int b    = blockIdx.x >> 9;        // 512 blocks per batch
  const int qblk = (blockIdx.x >> 1) & 255;
  const int half = blockIdx.x & 1;
  const int lane = threadIdx.x & 63;
  const int wave = threadIdx.x >> 6;
  const int gq   = b*Nn + qblk*64 + lane;  // global query id [0,65536)
  const float* op = oxyz + (size_t)gq*3;
  const float px = op[0], py = op[1], pz = op[2];
  const float qq = __fadd_rn(__fadd_rn(__fmul_rn(px,px), __fmul_rn(py,py)), __fmul_rn(pz,pz));
  const f32x2 px2 = {px,px}, py2 = {py,py}, pz2 = {pz,pz}, qq2 = {qq,qq};
  const f32x2 m2  = {-2.0f,-2.0f};

  const float* sx = sxyz + (size_t)b*Sn*3;
  const int slice = half*4 + wave;         // 0..7, ascending key ranges
  const int sbase = half*2048 + wave*512;  // A:[sbase,+256)  B:[sbase+256,+256)

  float ax, ay, az, bx, by, bz;
  {
    int ja = sbase + lane, jb = ja + 256;
    ax=sx[ja*3+0]; ay=sx[ja*3+1]; az=sx[ja*3+2];
    bx=sx[jb*3+0]; by=sx[jb*3+1]; bz=sx[jb*3+2];
  }
  {
    float assv = __fadd_rn(__fadd_rn(__fmul_rn(ax,ax), __fmul_rn(ay,ay)), __fmul_rn(az,az));
    float bssv = __fadd_rn(__fadd_rn(__fmul_rn(bx,bx), __fmul_rn(by,by)), __fmul_rn(bz,bz));
    cb[wave][0][0][lane] = make_float4(ax, bx, ay, by);
    cb[wave][0][1][lane] = make_float4(az, bz, assv, bssv);
  }

  float dA0=3.4e38f,dA1=3.4e38f,dA2=3.4e38f; int iA0=0,iA1=0,iA2=0;
  float dB0=3.4e38f,dB1=3.4e38f,dB2=3.4e38f; int iB0=0,iB1=0,iB2=0;

  int cur = 0;
  for (int c = 0; c < 4; ++c){
    if (c < 3){                          // next chunk's loads EARLY
      int ja = sbase + (c+1)*64 + lane, jb = ja + 256;
      ax=sx[ja*3+0]; ay=sx[ja*3+1]; az=sx[ja*3+2];
      bx=sx[jb*3+0]; by=sx[jb*3+1]; bz=sx[jb*3+2];
    }
    const int base = sbase + c*64;       // chain-A index base this chunk
    #pragma unroll 8
    for (int i = 0; i < 64; ++i){
      float4 lo = cb[wave][cur][0][i];   // broadcast b128
      float4 hi = cb[wave][cur][1][i];
      f32x2 kx2  = {lo.x, lo.y};
      f32x2 ky2  = {lo.z, lo.w};
      f32x2 kz2  = {hi.x, hi.y};
      f32x2 kss2 = {hi.z, hi.w};
      f32x2 dot = kx2 * px2;
      dot = __builtin_elementwise_fma(ky2, py2, dot);
      dot = __builtin_elementwise_fma(kz2, pz2, dot);
      f32x2 sm = qq2 + kss2;
      f32x2 dd = __builtin_elementwise_fma(m2, dot, sm);
      top3_bf(dd.x, base + i,       dA0,dA1,dA2, iA0,iA1,iA2);
      top3_bf(dd.y, base + i + 256, dB0,dB1,dB2, iB0,iB1,iB2);
    }
    if (c < 3){                          // write next chunk AFTER the scan
      int nxt = cur ^ 1;
      float assv = __fadd_rn(__fadd_rn(__fmul_rn(ax,ax), __fmul_rn(ay,ay)), __fmul_rn(az,az));
      float bssv = __fadd_rn(__fadd_rn(__fmul_rn(bx,bx), __fmul_rn(by,by)), __fmul_rn(bz,bz));
      cb[wave][nxt][0][lane] = make_float4(ax, bx, ay, by);
      cb[wave][nxt][1][lane] = make_float4(az, bz, assv, bssv);
      cur = nxt;
    }
  }

  // merge B into A (A indices < B indices -> strict '<' correct), write partial
  top3_insert(dB0, iB0, dA0,dA1,dA2, iA0,iA1,iA2);
  top3_insert(dB1, iB1, dA0,dA1,dA2, iA0,iA1,iA2);
  top3_insert(dB2, iB2, dA0,dA1,dA2, iA0,iA1,iA2);
  PD[(slice*3+0)*MTOT + gq] = dA0;
  PD[(slice*3+1)*MTOT + gq] = dA1;
  PD[(slice*3+2)*MTOT + gq] = dA2;
  PI[(slice*3+0)*MTOT + gq] = iA0;
  PI[(slice*3+1)*MTOT + gq] = iA1;
  PI[(slice*3+2)*MTOT + gq] = iA2;
}

// merge 8 slice-partials per query (ascending slice = ascending key range,
// strict '<' => reference top_k tie-break), compute weights, write kw/ki.
__global__ __launch_bounds__(256) void knnmerge_kernel(
    const float* __restrict__ PD, const int* __restrict__ PI,
    float* __restrict__ kw, int* __restrict__ ki)
{
  const int gq = blockIdx.x*256 + threadIdx.x;   // 0..65535
  float e0=3.4e38f, e1=3.4e38f, e2=3.4e38f;
  int   j0=0, j1=0, j2=0;
  #pragma unroll
  for (int s = 0; s < 8; ++s){
    #pragma unroll
    for (int j = 0; j < 3; ++j){
      float d = PD[(s*3+j)*MTOT + gq];
      int   i = PI[(s*3+j)*MTOT + gq];
      top3_insert(d, i, e0,e1,e2, j0,j1,j2);
    }
  }
  float wa = 1.0f/(e0+1e-8f), wb = 1.0f/(e1+1e-8f), wc = 1.0f/(e2+1e-8f);
  float sm = __fadd_rn(__fadd_rn(wa, wb), wc);
  size_t base = (size_t)gq*3;
  kw[base+0] = wa/sm; kw[base+1] = wb/sm; kw[base+2] = wc/sm;
  ki[base+0] = j0;    ki[base+1] = j1;    ki[base+2] = j2;
}

// ------------- interpolate + concat -> x [M][384] bf16 -------------
__global__ __launch_bounds__(256) void interp_kernel(
    const float* __restrict__ sfeat, const float* __restrict__ ofeat,
    const float* __restrict__ kw, const int* __restrict__ ki,
    unsigned short* __restrict__ X)
{
  const int c  = threadIdx.x;          // channel 0..255
  const int m0 = blockIdx.x * 16;      // 16 points per block
  for (int p = 0; p < 16; ++p){
    const int m = m0 + p;
    const int b = m >> 14;             // N = 16384
    const float w0v = kw[(size_t)m*3+0], w1v = kw[(size_t)m*3+1], w2v = kw[(size_t)m*3+2];
    const int   i0  = ki[(size_t)m*3+0], i1  = ki[(size_t)m*3+1], i2  = ki[(size_t)m*3+2];
    const float* sb = sfeat + (size_t)b * Sn * CSn;
    float v = __fmaf_rn(w2v, sb[(size_t)i2*CSn + c],
              __fmaf_rn(w1v, sb[(size_t)i1*CSn + c],
              __fmul_rn(w0v, sb[(size_t)i0*CSn + c])));
    X[(size_t)m*CINn + COn + c] = f2bf(v);
    if (c < COn) X[(size_t)m*CINn + c] = f2bf(ofeat[(size_t)m*COn + c]);
  }
}

// ------------- fp32 -> bf16 weight conversion -------------
__global__ __launch_bounds__(256) void cvtw_kernel(
    const float* __restrict__ w0, const float* __restrict__ w1,
    unsigned short* __restrict__ w0b, unsigned short* __restrict__ w1b)
{
  int i = blockIdx.x*256 + threadIdx.x;
  if (i < 256*384) w0b[i] = f2bf(w0[i]);
  int j = i - 256*384;
  if (j >= 0 && j < 256*256) w1b[j] = f2bf(w1[j]);
}

// ------------- GEMM: Y[M][256] = A[M][KDIM] @ W[256][KDIM]^T + bias ----------
// BM=128, BN=256 (full), BK=64. 4 waves, wave w owns cols [w*64, w*64+64).
// BNRELU prologue computes BN0 scale/shift IN-KERNEL from gemm0's stats,
// then A' = relu(A*scale + shift) during staging.
// Epilogue: bf16 store + per-channel sum/sumsq atomics for BN stats.
template<int KDIM, bool BNRELU>
__global__ __launch_bounds__(256) void gemm_kernel(
    const unsigned short* __restrict__ A,
    const unsigned short* __restrict__ W,
    const float* __restrict__ bias,
    const float* __restrict__ s0sum,
    const float* __restrict__ s0sq,
    const float* __restrict__ bng,
    const float* __restrict__ bnbt,
    unsigned short* __restrict__ Y,
    float* __restrict__ osum,
    float* __restrict__ osq)
{
  __shared__ unsigned short As[128*64];   // 16 KB, XOR-swizzled 16B chunks
  __shared__ unsigned short Bs[256*64];   // 32 KB
  __shared__ float lsc[256], lsh[256];
  const int tid  = threadIdx.x;
  const int lane = tid & 63;
  const int wave = tid >> 6;
  const size_t mbase = (size_t)blockIdx.x * 128;
  if constexpr (BNRELU){
    float mean = s0sum[tid] * (1.0f/65536.0f);
    float var  = s0sq[tid] * (1.0f/65536.0f) - mean*mean;
    float s = bng[tid] / sqrtf(var + 1e-5f);
    lsc[tid] = s;
    lsh[tid] = __fmaf_rn(-mean, s, bnbt[tid]);
  }
  f32x4 acc[8][4];
  #pragma unroll
  for (int m2 = 0; m2 < 8; ++m2)
    #pragma unroll
    for (int n2 = 0; n2 < 4; ++n2) acc[m2][n2] = f32x4{0.f,0.f,0.f,0.f};
  __syncthreads();

  for (int k0 = 0; k0 < KDIM; k0 += 64){
    if (k0) __syncthreads();
    // stage A: 128 rows x 8 chunks(16B) = 1024 chunks, 4/thread
    #pragma unroll
    for (int i = 0; i < 4; ++i){
      int cid = tid + 256*i;
      int row = cid >> 3, c8 = cid & 7;
      short8 v = *reinterpret_cast<const short8*>(A + (mbase+row)*KDIM + k0 + c8*8);
      if constexpr (BNRELU){
        #pragma unroll
        for (int j = 0; j < 8; ++j){
          int kc = k0 + c8*8 + j;
          float f = bf2f((unsigned short)v[j]);
          f = fmaxf(__fmaf_rn(f, lsc[kc], lsh[kc]), 0.0f);
          v[j] = (short)f2bf(f);
        }
      }
      *reinterpret_cast<short8*>(reinterpret_cast<char*>(As) + row*128 + ((c8 ^ (row&7)) << 4)) = v;
    }
    // stage B (weights): 256 rows x 8 chunks = 2048 chunks, 8/thread
    #pragma unroll
    for (int i = 0; i < 8; ++i){
      int cid = tid + 256*i;
      int row = cid >> 3, c8 = cid & 7;
      short8 v = *reinterpret_cast<const short8*>(W + (size_t)row*KDIM + k0 + c8*8);
      *reinterpret_cast<short8*>(reinterpret_cast<char*>(Bs) + row*128 + ((c8 ^ (row&7)) << 4)) = v;
    }
    __syncthreads();
    #pragma unroll
    for (int kk = 0; kk < 2; ++kk){
      short8 af[8], bv[4];
      #pragma unroll
      for (int m2 = 0; m2 < 8; ++m2){
        int row = m2*16 + (lane & 15);
        int c8  = kk*4 + (lane >> 4);
        af[m2] = *reinterpret_cast<const short8*>(reinterpret_cast<char*>(As) + row*128 + ((c8 ^ (row&7)) << 4));
      }
      #pragma unroll
      for (int n2 = 0; n2 < 4; ++n2){
        int row = wave*64 + n2*16 + (lane & 15);
        int c8  = kk*4 + (lane >> 4);
        bv[n2] = *reinterpret_cast<const short8*>(reinterpret_cast<char*>(Bs) + row*128 + ((c8 ^ (row&7)) << 4));
      }
      #pragma unroll
      for (int m2 = 0; m2 < 8; ++m2)
        #pragma unroll
        for (int n2 = 0; n2 < 4; ++n2)
          acc[m2][n2] = __builtin_amdgcn_mfma_f32_16x16x32_bf16(af[m2], bv[n2], acc[m2][n2], 0, 0, 0);
    }
  }

  // epilogue: C/D layout col = lane&15, row = (lane>>4)*4 + j  [m89-verified]
  const int colg0 = wave*64;
  float spart[4] = {0,0,0,0}, qpart[4] = {0,0,0,0};
  #pragma unroll
  for (int m2 = 0; m2 < 8; ++m2){
    #pragma unroll
    for (int n2 = 0; n2 < 4; ++n2){
      const int gc  = colg0 + n2*16 + (lane & 15);
      const float bvv = bias[gc];
      #pragma unroll
      for (int j = 0; j < 4; ++j){
        float yv = acc[m2][n2][j] + bvv;
        size_t gr = mbase + m2*16 + (lane>>4)*4 + j;
        Y[gr*256 + gc] = f2bf(yv);
        spart[n2] += yv;
        qpart[n2] = __fmaf_rn(yv, yv, qpart[n2]);
      }
    }
  }
  #pragma unroll
  for (int n2 = 0; n2 < 4; ++n2){
    float s = spart[n2], q = qpart[n2];
    s += __shfl_xor(s, 16); q += __shfl_xor(q, 16);
    s += __shfl_xor(s, 32); q += __shfl_xor(q, 32);
    if (lane < 16){
      int gc = colg0 + n2*16 + lane;
      atomicAdd(&osum[gc], s);
      atomicAdd(&osq[gc], q);
    }
  }
}

// ------------- final BN1 + ReLU -> fp32 out (BN finalize folded in) -------------
__global__ __launch_bounds__(256) void apply_kernel(
    const unsigned short* __restrict__ y,
    const float* __restrict__ s1sum, const float* __restrict__ s1sq,
    const float* __restrict__ g, const float* __restrict__ bt,
    float* __restrict__ out)
{
  __shared__ float ssc[256], ssh[256];
  {
    int c = threadIdx.x;
    float mean = s1sum[c] * (1.0f/65536.0f);
    float var  = s1sq[c] * (1.0f/65536.0f) - mean*mean;
    float s = g[c] / sqrtf(var + 1e-5f);
    ssc[c] = s;
    ssh[c] = __fmaf_rn(-mean, s, bt[c]);
  }
  __syncthreads();
  const int t = blockIdx.x*256 + threadIdx.x;
  const size_t base = (size_t)t * 8;
  const int c0 = (int)(base & 255);
  short8 v = *reinterpret_cast<const short8*>(y + base);
  float r[8];
  #pragma unroll
  for (int j = 0; j < 8; ++j){
    float f = bf2f((unsigned short)v[j]);
    f = __fmaf_rn(f, ssc[c0+j], ssh[c0+j]);
    r[j] = fmaxf(f, 0.0f);
  }
  float4 o0, o1;
  o0.x=r[0]; o0.y=r[1]; o0.z=r[2]; o0.w=r[3];
  o1.x=r[4]; o1.y=r[5]; o1.z=r[6]; o1.w=r[7];
  *reinterpret_cast<float4*>(out + base)     = o0;
  *reinterpret_cast<float4*>(out + base + 4) = o1;
}

// ---------------- workspace layout ----------------
constexpr size_t WS_STATS = 0;                                  // 4*256 f32
constexpr size_t WS_W0B   = 8192;                               // 98304 bf16
constexpr size_t WS_W1B   = WS_W0B + 196608;                    // 65536 bf16
constexpr size_t WS_KW    = WS_W1B + 131072;                    // M*3 f32
constexpr size_t WS_KI    = WS_KW + 786432;                     // M*3 i32
constexpr size_t WS_X     = 4194304;                            // M*384 bf16 (50.3 MB)
constexpr size_t WS_Y0    = WS_X + (size_t)MTOT*CINn*2;         // M*256 bf16 (33.5 MB)
// PD/PI (8*3*65536 f32/i32 = 6.3 MB each) live in the X region: they are dead
// before interp_kernel writes X. Y1 reuses X region too. Peak ws ~88 MB.
constexpr size_t WS_PD    = WS_X;
constexpr size_t WS_PI    = WS_X + (size_t)8*3*MTOT*4;

extern "C" void kernel_launch(void* const* d_in, const int* in_sizes, int n_in,
                              void* d_out, int out_size, void* d_ws, size_t ws_size,
                              hipStream_t stream)
{
  const float* sxyz  = (const float*)d_in[0];
  const float* sfeat = (const float*)d_in[1];
  const float* oxyz  = (const float*)d_in[2];
  const float* ofeat = (const float*)d_in[3];
  const float* w0    = (const float*)d_in[4];
  const float* b0    = (const float*)d_in[5];
  const float* g0    = (const float*)d_in[6];
  const float* bt0   = (const float*)d_in[7];
  const float* w1    = (const float*)d_in[8];
  const float* b1    = (const float*)d_in[9];
  const float* g1    = (const float*)d_in[10];
  const float* bt1   = (const float*)d_in[11];
  // d_in[12] = k (always 3, hard-coded)

  char* ws = (char*)d_ws;
  float* stats  = (float*)(ws + WS_STATS);   // sum0,ssq0,sum1,ssq1
  unsigned short* w0b = (unsigned short*)(ws + WS_W0B);
  unsigned short* w1b = (unsigned short*)(ws + WS_W1B);
  float* kw = (float*)(ws + WS_KW);
  int*   ki = (int*)(ws + WS_KI);
  float* PD = (float*)(ws + WS_PD);
  int*   PI = (int*)(ws + WS_PI);
  unsigned short* X  = (unsigned short*)(ws + WS_X);
  unsigned short* Y0 = (unsigned short*)(ws + WS_Y0);
  unsigned short* Y1 = (unsigned short*)(ws + WS_X);   // reuse

  hipMemsetAsync(stats, 0, 4*256*sizeof(float), stream);
  cvtw_kernel<<<640, 256, 0, stream>>>(w0, w1, w0b, w1b);
  knn_kernel<<<2048, 256, 0, stream>>>(sxyz, oxyz, PD, PI);
  knnmerge_kernel<<<MTOT/256, 256, 0, stream>>>(PD, PI, kw, ki);
  interp_kernel<<<MTOT/16, 256, 0, stream>>>(sfeat, ofeat, kw, ki, X);
  gemm_kernel<CINn, false><<<MTOT/128, 256, 0, stream>>>(
      X, w0b, b0, nullptr, nullptr, nullptr, nullptr, Y0, stats, stats + 256);
  gemm_kernel<256, true><<<MTOT/128, 256, 0, stream>>>(
      Y0, w1b, b1, stats, stats + 256, g0, bt0, Y1, stats + 512, stats + 768);
  apply_kernel<<<(MTOT*256)/(256*8), 256, 0, stream>>>(
      Y1, stats + 512, stats + 768, g1, bt1, (float*)d_out);
}

// Round 10
// 262.519 us; speedup vs baseline: 1.0568x; 1.0568x over previous
//
#include <hip/hip_runtime.h>
#include <hip/hip_bf16.h>
#include <cstdint>
#include <cstddef>

// Problem constants (fixed shapes)
#define Bn   4
#define Sn   4096
#define Nn   16384
#define CSn  256
#define COn  128
#define CINn 384
#define MTOT 65536   // B*N

using short8 = short __attribute__((ext_vector_type(8)));
using f32x4  = float __attribute__((ext_vector_type(4)));
using f32x2  = float __attribute__((ext_vector_type(2)));

static __device__ __forceinline__ float bf2f(unsigned short u){
  unsigned int x = ((unsigned int)u) << 16;
  return __builtin_bit_cast(float, x);
}
static __device__ __forceinline__ unsigned short f2bf(float f){
  unsigned int x = __builtin_bit_cast(unsigned int, f);
  x += 0x7fffu + ((x >> 16) & 1u);   // RNE
  return (unsigned short)(x >> 16);
}

// ---------------- KNN ----------------
// branchy insert used only in tiny merges (sorted-triple inputs)
static __device__ __forceinline__ void top3_insert(float d, int s,
    float& d0, float& d1, float& d2, int& i0, int& i1, int& i2){
  if (d < d2){
    if (d < d1){
      d2 = d1; i2 = i1;
      if (d < d0){ d1 = d0; i1 = i0; d0 = d; i0 = s; }
      else       { d1 = d;  i1 = s; }
    } else { d2 = d; i2 = s; }
  }
}

// 2048 blocks x 256 threads (4 waves), fully wave-independent (NO barriers).
// Geometry identical to R9 (verified: 0 conflicts, 56% occ). Inner loop is
// now inline asm with a GUARANTEED instruction count (~31/pair-iter vs the
// ~80 the C++ lowering produced):
//  - dist: 5x VOP3P packed-fp32 (v_pk_mul/fma/add) -> both chains at once;
//    per-component IEEE rounding == scalar chain -> distances bit-identical.
//  - maint per chain: 3x v_cmp_lt_f32 (sgpr pairs), med3/med3/min on OLD
//    values (== top3_bf), 5x v_cndmask_b32 (strict '<' tie-break preserved).
// Each wave writes its top-3 partial to PD/PI; knnmerge merges 8 slices in
// ascending key order (strict '<') -> reference top_k tie-break exact.
__global__ __launch_bounds__(256) void knn_kernel(
    const float* __restrict__ sxyz, const float* __restrict__ oxyz,
    float* __restrict__ PD, int* __restrict__ PI)
{
  __shared__ float4 cb[4][2][2][64];   // 16 KB: [wave][dbuf][plane][pair]

  const int b    = blockIdx.x >> 9;        // 512 blocks per batch
  const int qblk = (blockIdx.x >> 1) & 255;
  const int half = blockIdx.x & 1;
  const int lane = threadIdx.x & 63;
  const int wave = threadIdx.x >> 6;
  const int gq   = b*Nn + qblk*64 + lane;  // global query id [0,65536)
  const float* op = oxyz + (size_t)gq*3;
  const float px = op[0], py = op[1], pz = op[2];
  const float qq = __fadd_rn(__fadd_rn(__fmul_rn(px,px), __fmul_rn(py,py)), __fmul_rn(pz,pz));
  const f32x2 px2 = {px,px}, py2 = {py,py}, pz2 = {pz,pz}, qq2 = {qq,qq};
  const f32x2 m2  = {-2.0f,-2.0f};

  const float* sx = sxyz + (size_t)b*Sn*3;
  const int slice = half*4 + wave;         // 0..7, ascending key ranges
  const int sbase = half*2048 + wave*512;  // A:[sbase,+256)  B:[sbase+256,+256)

  float ax, ay, az, bx, by, bz;
  {
    int ja = sbase + lane, jb = ja + 256;
    ax=sx[ja*3+0]; ay=sx[ja*3+1]; az=sx[ja*3+2];
    bx=sx[jb*3+0]; by=sx[jb*3+1]; bz=sx[jb*3+2];
  }
  {
    float assv = __fadd_rn(__fadd_rn(__fmul_rn(ax,ax), __fmul_rn(ay,ay)), __fmul_rn(az,az));
    float bssv = __fadd_rn(__fadd_rn(__fmul_rn(bx,bx), __fmul_rn(by,by)), __fmul_rn(bz,bz));
    cb[wave][0][0][lane] = make_float4(ax, bx, ay, by);
    cb[wave][0][1][lane] = make_float4(az, bz, assv, bssv);
  }

  float dA0=3.4e38f,dA1=3.4e38f,dA2=3.4e38f; int iA0=0,iA1=0,iA2=0;
  float dB0=3.4e38f,dB1=3.4e38f,dB2=3.4e38f; int iB0=0,iB1=0,iB2=0;

  int cur = 0;
  for (int c = 0; c < 4; ++c){
    if (c < 3){                          // next chunk's loads EARLY
      int ja = sbase + (c+1)*64 + lane, jb = ja + 256;
      ax=sx[ja*3+0]; ay=sx[ja*3+1]; az=sx[ja*3+2];
      bx=sx[jb*3+0]; by=sx[jb*3+1]; bz=sx[jb*3+2];
    }
    const int base = sbase + c*64;       // chain-A index base this chunk
    #pragma unroll 8
    for (int i = 0; i < 64; ++i){
      float4 lo = cb[wave][cur][0][i];   // broadcast ds_read_b128
      float4 hi = cb[wave][cur][1][i];
      f32x2 kx  = {lo.x, lo.y};
      f32x2 ky  = {lo.z, lo.w};
      f32x2 kz  = {hi.x, hi.y};
      f32x2 kss = {hi.z, hi.w};
      f32x2 dot, dd;
      // dist: dd = fma(-2, dot, qq+ss), dot = fma(z,fma(y,mul(x))) — packed
      asm("v_pk_mul_f32 %0, %2, %6\n\t"
          "v_pk_fma_f32 %0, %3, %7, %0\n\t"
          "v_pk_fma_f32 %0, %4, %8, %0\n\t"
          "v_pk_add_f32 %1, %9, %5\n\t"
          "v_pk_fma_f32 %1, %10, %0, %1"
          : "=&v"(dot), "=&v"(dd)
          : "v"(kx), "v"(ky), "v"(kz), "v"(kss),
            "v"(px2), "v"(py2), "v"(pz2), "v"(qq2), "v"(m2));
      const float ddA = dd.x, ddB = dd.y;
      {
        unsigned long long c0, c1, c2; int t;
        asm("v_cmp_lt_f32 %[c0], %[dd], %[d0]\n\t"
            "v_cmp_lt_f32 %[c1], %[dd], %[d1]\n\t"
            "v_cmp_lt_f32 %[c2], %[dd], %[d2]\n\t"
            "v_med3_f32 %[d2], %[dd], %[d1], %[d2]\n\t"
            "v_med3_f32 %[d1], %[dd], %[d0], %[d1]\n\t"
            "v_min_f32  %[d0], %[dd], %[d0]\n\t"
            "v_cndmask_b32 %[t], %[idx], %[i1], %[c1]\n\t"
            "v_cndmask_b32 %[i2], %[i2], %[t], %[c2]\n\t"
            "v_cndmask_b32 %[t], %[idx], %[i0], %[c0]\n\t"
            "v_cndmask_b32 %[i1], %[i1], %[t], %[c1]\n\t"
            "v_cndmask_b32 %[i0], %[i0], %[idx], %[c0]"
            : [d0]"+v"(dA0), [d1]"+v"(dA1), [d2]"+v"(dA2),
              [i0]"+v"(iA0), [i1]"+v"(iA1), [i2]"+v"(iA2),
              [t]"=&v"(t), [c0]"=&s"(c0), [c1]"=&s"(c1), [c2]"=&s"(c2)
            : [dd]"v"(ddA), [idx]"v"(base + i));
      }
      {
        unsigned long long c0, c1, c2; int t;
        asm("v_cmp_lt_f32 %[c0], %[dd], %[d0]\n\t"
            "v_cmp_lt_f32 %[c1], %[dd], %[d1]\n\t"
            "v_cmp_lt_f32 %[c2], %[dd], %[d2]\n\t"
            "v_med3_f32 %[d2], %[dd], %[d1], %[d2]\n\t"
            "v_med3_f32 %[d1], %[dd], %[d0], %[d1]\n\t"
            "v_min_f32  %[d0], %[dd], %[d0]\n\t"
            "v_cndmask_b32 %[t], %[idx], %[i1], %[c1]\n\t"
            "v_cndmask_b32 %[i2], %[i2], %[t], %[c2]\n\t"
            "v_cndmask_b32 %[t], %[idx], %[i0], %[c0]\n\t"
            "v_cndmask_b32 %[i1], %[i1], %[t], %[c1]\n\t"
            "v_cndmask_b32 %[i0], %[i0], %[idx], %[c0]"
            : [d0]"+v"(dB0), [d1]"+v"(dB1), [d2]"+v"(dB2),
              [i0]"+v"(iB0), [i1]"+v"(iB1), [i2]"+v"(iB2),
              [t]"=&v"(t), [c0]"=&s"(c0), [c1]"=&s"(c1), [c2]"=&s"(c2)
            : [dd]"v"(ddB), [idx]"v"(base + i + 256));
      }
    }
    if (c < 3){                          // write next chunk AFTER the scan
      int nxt = cur ^ 1;
      float assv = __fadd_rn(__fadd_rn(__fmul_rn(ax,ax), __fmul_rn(ay,ay)), __fmul_rn(az,az));
      float bssv = __fadd_rn(__fadd_rn(__fmul_rn(bx,bx), __fmul_rn(by,by)), __fmul_rn(bz,bz));
      cb[wave][nxt][0][lane] = make_float4(ax, bx, ay, by);
      cb[wave][nxt][1][lane] = make_float4(az, bz, assv, bssv);
      cur = nxt;
    }
  }

  // merge B into A (A indices < B indices -> strict '<' correct), write partial
  top3_insert(dB0, iB0, dA0,dA1,dA2, iA0,iA1,iA2);
  top3_insert(dB1, iB1, dA0,dA1,dA2, iA0,iA1,iA2);
  top3_insert(dB2, iB2, dA0,dA1,dA2, iA0,iA1,iA2);
  PD[(slice*3+0)*MTOT + gq] = dA0;
  PD[(slice*3+1)*MTOT + gq] = dA1;
  PD[(slice*3+2)*MTOT + gq] = dA2;
  PI[(slice*3+0)*MTOT + gq] = iA0;
  PI[(slice*3+1)*MTOT + gq] = iA1;
  PI[(slice*3+2)*MTOT + gq] = iA2;
}

// merge 8 slice-partials per query (ascending slice = ascending key range,
// strict '<' => reference top_k tie-break), compute weights, write kw/ki.
__global__ __launch_bounds__(256) void knnmerge_kernel(
    const float* __restrict__ PD, const int* __restrict__ PI,
    float* __restrict__ kw, int* __restrict__ ki)
{
  const int gq = blockIdx.x*256 + threadIdx.x;   // 0..65535
  float e0=3.4e38f, e1=3.4e38f, e2=3.4e38f;
  int   j0=0, j1=0, j2=0;
  #pragma unroll
  for (int s = 0; s < 8; ++s){
    #pragma unroll
    for (int j = 0; j < 3; ++j){
      float d = PD[(s*3+j)*MTOT + gq];
      int   i = PI[(s*3+j)*MTOT + gq];
      top3_insert(d, i, e0,e1,e2, j0,j1,j2);
    }
  }
  float wa = 1.0f/(e0+1e-8f), wb = 1.0f/(e1+1e-8f), wc = 1.0f/(e2+1e-8f);
  float sm = __fadd_rn(__fadd_rn(wa, wb), wc);
  size_t base = (size_t)gq*3;
  kw[base+0] = wa/sm; kw[base+1] = wb/sm; kw[base+2] = wc/sm;
  ki[base+0] = j0;    ki[base+1] = j1;    ki[base+2] = j2;
}

// ------------- interpolate + concat -> x [M][384] bf16 -------------
__global__ __launch_bounds__(256) void interp_kernel(
    const float* __restrict__ sfeat, const float* __restrict__ ofeat,
    const float* __restrict__ kw, const int* __restrict__ ki,
    unsigned short* __restrict__ X)
{
  const int c  = threadIdx.x;          // channel 0..255
  const int m0 = blockIdx.x * 16;      // 16 points per block
  for (int p = 0; p < 16; ++p){
    const int m = m0 + p;
    const int b = m >> 14;             // N = 16384
    const float w0v = kw[(size_t)m*3+0], w1v = kw[(size_t)m*3+1], w2v = kw[(size_t)m*3+2];
    const int   i0  = ki[(size_t)m*3+0], i1  = ki[(size_t)m*3+1], i2  = ki[(size_t)m*3+2];
    const float* sb = sfeat + (size_t)b * Sn * CSn;
    float v = __fmaf_rn(w2v, sb[(size_t)i2*CSn + c],
              __fmaf_rn(w1v, sb[(size_t)i1*CSn + c],
              __fmul_rn(w0v, sb[(size_t)i0*CSn + c])));
    X[(size_t)m*CINn + COn + c] = f2bf(v);
    if (c < COn) X[(size_t)m*CINn + c] = f2bf(ofeat[(size_t)m*COn + c]);
  }
}

// ------------- fp32 -> bf16 weight conversion -------------
__global__ __launch_bounds__(256) void cvtw_kernel(
    const float* __restrict__ w0, const float* __restrict__ w1,
    unsigned short* __restrict__ w0b, unsigned short* __restrict__ w1b)
{
  int i = blockIdx.x*256 + threadIdx.x;
  if (i < 256*384) w0b[i] = f2bf(w0[i]);
  int j = i - 256*384;
  if (j >= 0 && j < 256*256) w1b[j] = f2bf(w1[j]);
}

// ------------- GEMM: Y[M][256] = A[M][KDIM] @ W[256][KDIM]^T + bias ----------
// BM=128, BN=256 (full), BK=64. 4 waves, wave w owns cols [w*64, w*64+64).
// BNRELU prologue computes BN0 scale/shift IN-KERNEL from gemm0's stats,
// then A' = relu(A*scale + shift) during staging.
// Epilogue: bf16 store + per-channel sum/sumsq atomics for BN stats.
template<int KDIM, bool BNRELU>
__global__ __launch_bounds__(256) void gemm_kernel(
    const unsigned short* __restrict__ A,
    const unsigned short* __restrict__ W,
    const float* __restrict__ bias,
    const float* __restrict__ s0sum,
    const float* __restrict__ s0sq,
    const float* __restrict__ bng,
    const float* __restrict__ bnbt,
    unsigned short* __restrict__ Y,
    float* __restrict__ osum,
    float* __restrict__ osq)
{
  __shared__ unsigned short As[128*64];   // 16 KB, XOR-swizzled 16B chunks
  __shared__ unsigned short Bs[256*64];   // 32 KB
  __shared__ float lsc[256], lsh[256];
  const int tid  = threadIdx.x;
  const int lane = tid & 63;
  const int wave = tid >> 6;
  const size_t mbase = (size_t)blockIdx.x * 128;
  if constexpr (BNRELU){
    float mean = s0sum[tid] * (1.0f/65536.0f);
    float var  = s0sq[tid] * (1.0f/65536.0f) - mean*mean;
    float s = bng[tid] / sqrtf(var + 1e-5f);
    lsc[tid] = s;
    lsh[tid] = __fmaf_rn(-mean, s, bnbt[tid]);
  }
  f32x4 acc[8][4];
  #pragma unroll
  for (int m2 = 0; m2 < 8; ++m2)
    #pragma unroll
    for (int n2 = 0; n2 < 4; ++n2) acc[m2][n2] = f32x4{0.f,0.f,0.f,0.f};
  __syncthreads();

  for (int k0 = 0; k0 < KDIM; k0 += 64){
    if (k0) __syncthreads();
    // stage A: 128 rows x 8 chunks(16B) = 1024 chunks, 4/thread
    #pragma unroll
    for (int i = 0; i < 4; ++i){
      int cid = tid + 256*i;
      int row = cid >> 3, c8 = cid & 7;
      short8 v = *reinterpret_cast<const short8*>(A + (mbase+row)*KDIM + k0 + c8*8);
      if constexpr (BNRELU){
        #pragma unroll
        for (int j = 0; j < 8; ++j){
          int kc = k0 + c8*8 + j;
          float f = bf2f((unsigned short)v[j]);
          f = fmaxf(__fmaf_rn(f, lsc[kc], lsh[kc]), 0.0f);
          v[j] = (short)f2bf(f);
        }
      }
      *reinterpret_cast<short8*>(reinterpret_cast<char*>(As) + row*128 + ((c8 ^ (row&7)) << 4)) = v;
    }
    // stage B (weights): 256 rows x 8 chunks = 2048 chunks, 8/thread
    #pragma unroll
    for (int i = 0; i < 8; ++i){
      int cid = tid + 256*i;
      int row = cid >> 3, c8 = cid & 7;
      short8 v = *reinterpret_cast<const short8*>(W + (size_t)row*KDIM + k0 + c8*8);
      *reinterpret_cast<short8*>(reinterpret_cast<char*>(Bs) + row*128 + ((c8 ^ (row&7)) << 4)) = v;
    }
    __syncthreads();
    #pragma unroll
    for (int kk = 0; kk < 2; ++kk){
      short8 af[8], bv[4];
      #pragma unroll
      for (int m2 = 0; m2 < 8; ++m2){
        int row = m2*16 + (lane & 15);
        int c8  = kk*4 + (lane >> 4);
        af[m2] = *reinterpret_cast<const short8*>(reinterpret_cast<char*>(As) + row*128 + ((c8 ^ (row&7)) << 4));
      }
      #pragma unroll
      for (int n2 = 0; n2 < 4; ++n2){
        int row = wave*64 + n2*16 + (lane & 15);
        int c8  = kk*4 + (lane >> 4);
        bv[n2] = *reinterpret_cast<const short8*>(reinterpret_cast<char*>(Bs) + row*128 + ((c8 ^ (row&7)) << 4));
      }
      #pragma unroll
      for (int m2 = 0; m2 < 8; ++m2)
        #pragma unroll
        for (int n2 = 0; n2 < 4; ++n2)
          acc[m2][n2] = __builtin_amdgcn_mfma_f32_16x16x32_bf16(af[m2], bv[n2], acc[m2][n2], 0, 0, 0);
    }
  }

  // epilogue: C/D layout col = lane&15, row = (lane>>4)*4 + j  [m89-verified]
  const int colg0 = wave*64;
  float spart[4] = {0,0,0,0}, qpart[4] = {0,0,0,0};
  #pragma unroll
  for (int m2 = 0; m2 < 8; ++m2){
    #pragma unroll
    for (int n2 = 0; n2 < 4; ++n2){
      const int gc  = colg0 + n2*16 + (lane & 15);
      const float bvv = bias[gc];
      #pragma unroll
      for (int j = 0; j < 4; ++j){
        float yv = acc[m2][n2][j] + bvv;
        size_t gr = mbase + m2*16 + (lane>>4)*4 + j;
        Y[gr*256 + gc] = f2bf(yv);
        spart[n2] += yv;
        qpart[n2] = __fmaf_rn(yv, yv, qpart[n2]);
      }
    }
  }
  #pragma unroll
  for (int n2 = 0; n2 < 4; ++n2){
    float s = spart[n2], q = qpart[n2];
    s += __shfl_xor(s, 16); q += __shfl_xor(q, 16);
    s += __shfl_xor(s, 32); q += __shfl_xor(q, 32);
    if (lane < 16){
      int gc = colg0 + n2*16 + lane;
      atomicAdd(&osum[gc], s);
      atomicAdd(&osq[gc], q);
    }
  }
}

// ------------- final BN1 + ReLU -> fp32 out (BN finalize folded in) -------------
__global__ __launch_bounds__(256) void apply_kernel(
    const unsigned short* __restrict__ y,
    const float* __restrict__ s1sum, const float* __restrict__ s1sq,
    const float* __restrict__ g, const float* __restrict__ bt,
    float* __restrict__ out)
{
  __shared__ float ssc[256], ssh[256];
  {
    int c = threadIdx.x;
    float mean = s1sum[c] * (1.0f/65536.0f);
    float var  = s1sq[c] * (1.0f/65536.0f) - mean*mean;
    float s = g[c] / sqrtf(var + 1e-5f);
    ssc[c] = s;
    ssh[c] = __fmaf_rn(-mean, s, bt[c]);
  }
  __syncthreads();
  const int t = blockIdx.x*256 + threadIdx.x;
  const size_t base = (size_t)t * 8;
  const int c0 = (int)(base & 255);
  short8 v = *reinterpret_cast<const short8*>(y + base);
  float r[8];
  #pragma unroll
  for (int j = 0; j < 8; ++j){
    float f = bf2f((unsigned short)v[j]);
    f = __fmaf_rn(f, ssc[c0+j], ssh[c0+j]);
    r[j] = fmaxf(f, 0.0f);
  }
  float4 o0, o1;
  o0.x=r[0]; o0.y=r[1]; o0.z=r[2]; o0.w=r[3];
  o1.x=r[4]; o1.y=r[5]; o1.z=r[6]; o1.w=r[7];
  *reinterpret_cast<float4*>(out + base)     = o0;
  *reinterpret_cast<float4*>(out + base + 4) = o1;
}

// ---------------- workspace layout ----------------
constexpr size_t WS_STATS = 0;                                  // 4*256 f32
constexpr size_t WS_W0B   = 8192;                               // 98304 bf16
constexpr size_t WS_W1B   = WS_W0B + 196608;                    // 65536 bf16
constexpr size_t WS_KW    = WS_W1B + 131072;                    // M*3 f32
constexpr size_t WS_KI    = WS_KW + 786432;                     // M*3 i32
constexpr size_t WS_X     = 4194304;                            // M*384 bf16 (50.3 MB)
constexpr size_t WS_Y0    = WS_X + (size_t)MTOT*CINn*2;         // M*256 bf16 (33.5 MB)
// PD/PI (8*3*65536 f32/i32 = 6.3 MB each) live in the X region: they are dead
// before interp_kernel writes X. Y1 reuses X region too. Peak ws ~88 MB.
constexpr size_t WS_PD    = WS_X;
constexpr size_t WS_PI    = WS_X + (size_t)8*3*MTOT*4;

extern "C" void kernel_launch(void* const* d_in, const int* in_sizes, int n_in,
                              void* d_out, int out_size, void* d_ws, size_t ws_size,
                              hipStream_t stream)
{
  const float* sxyz  = (const float*)d_in[0];
  const float* sfeat = (const float*)d_in[1];
  const float* oxyz  = (const float*)d_in[2];
  const float* ofeat = (const float*)d_in[3];
  const float* w0    = (const float*)d_in[4];
  const float* b0    = (const float*)d_in[5];
  const float* g0    = (const float*)d_in[6];
  const float* bt0   = (const float*)d_in[7];
  const float* w1    = (const float*)d_in[8];
  const float* b1    = (const float*)d_in[9];
  const float* g1    = (const float*)d_in[10];
  const float* bt1   = (const float*)d_in[11];
  // d_in[12] = k (always 3, hard-coded)

  char* ws = (char*)d_ws;
  float* stats  = (float*)(ws + WS_STATS);   // sum0,ssq0,sum1,ssq1
  unsigned short* w0b = (unsigned short*)(ws + WS_W0B);
  unsigned short* w1b = (unsigned short*)(ws + WS_W1B);
  float* kw = (float*)(ws + WS_KW);
  int*   ki = (int*)(ws + WS_KI);
  float* PD = (float*)(ws + WS_PD);
  int*   PI = (int*)(ws + WS_PI);
  unsigned short* X  = (unsigned short*)(ws + WS_X);
  unsigned short* Y0 = (unsigned short*)(ws + WS_Y0);
  unsigned short* Y1 = (unsigned short*)(ws + WS_X);   // reuse

  hipMemsetAsync(stats, 0, 4*256*sizeof(float), stream);
  cvtw_kernel<<<640, 256, 0, stream>>>(w0, w1, w0b, w1b);
  knn_kernel<<<2048, 256, 0, stream>>>(sxyz, oxyz, PD, PI);
  knnmerge_kernel<<<MTOT/256, 256, 0, stream>>>(PD, PI, kw, ki);
  interp_kernel<<<MTOT/16, 256, 0, stream>>>(sfeat, ofeat, kw, ki, X);
  gemm_kernel<CINn, false><<<MTOT/128, 256, 0, stream>>>(
      X, w0b, b0, nullptr, nullptr, nullptr, nullptr, Y0, stats, stats + 256);
  gemm_kernel<256, true><<<MTOT/128, 256, 0, stream>>>(
      Y0, w1b, b1, stats, stats + 256, g0, bt0, Y1, stats + 512, stats + 768);
  apply_kernel<<<(MTOT*256)/(256*8), 256, 0, stream>>>(
      Y1, stats + 512, stats + 768, g1, bt1, (float*)d_out);
}

// Round 11
// 240.411 us; speedup vs baseline: 1.1540x; 1.0920x over previous
//
#include <hip/hip_runtime.h>
#include <hip/hip_bf16.h>
#include <cstdint>
#include <cstddef>

// Problem constants (fixed shapes)
#define Bn   4
#define Sn   4096
#define Nn   16384
#define CSn  256
#define COn  128
#define CINn 384
#define MTOT 65536   // B*N

using short8 = short __attribute__((ext_vector_type(8)));
using f32x4  = float __attribute__((ext_vector_type(4)));
using f32x2  = float __attribute__((ext_vector_type(2)));

static __device__ __forceinline__ float bf2f(unsigned short u){
  unsigned int x = ((unsigned int)u) << 16;
  return __builtin_bit_cast(float, x);
}
static __device__ __forceinline__ unsigned short f2bf(float f){
  unsigned int x = __builtin_bit_cast(unsigned int, f);
  x += 0x7fffu + ((x >> 16) & 1u);   // RNE
  return (unsigned short)(x >> 16);
}

// ---------------- KNN ----------------
// branchy insert used only in tiny merges (sorted-triple inputs)
static __device__ __forceinline__ void top3_insert(float d, int s,
    float& d0, float& d1, float& d2, int& i0, int& i1, int& i2){
  if (d < d2){
    if (d < d1){
      d2 = d1; i2 = i1;
      if (d < d0){ d1 = d0; i1 = i0; d0 = d; i0 = s; }
      else       { d1 = d;  i1 = s; }
    } else { d2 = d; i2 = s; }
  }
}

// 2048 blocks x 256 threads (4 waves), fully wave-independent (NO barriers).
// R10-frozen: inline-asm inner loop (packed fp32 dist + branch-free maint),
// distances bit-identical to reference chain, strict-'<' ascending order.
__global__ __launch_bounds__(256) void knn_kernel(
    const float* __restrict__ sxyz, const float* __restrict__ oxyz,
    float* __restrict__ PD, int* __restrict__ PI)
{
  __shared__ float4 cb[4][2][2][64];   // 16 KB: [wave][dbuf][plane][pair]

  const int b    = blockIdx.x >> 9;        // 512 blocks per batch
  const int qblk = (blockIdx.x >> 1) & 255;
  const int half = blockIdx.x & 1;
  const int lane = threadIdx.x & 63;
  const int wave = threadIdx.x >> 6;
  const int gq   = b*Nn + qblk*64 + lane;  // global query id [0,65536)
  const float* op = oxyz + (size_t)gq*3;
  const float px = op[0], py = op[1], pz = op[2];
  const float qq = __fadd_rn(__fadd_rn(__fmul_rn(px,px), __fmul_rn(py,py)), __fmul_rn(pz,pz));
  const f32x2 px2 = {px,px}, py2 = {py,py}, pz2 = {pz,pz}, qq2 = {qq,qq};
  const f32x2 m2  = {-2.0f,-2.0f};

  const float* sx = sxyz + (size_t)b*Sn*3;
  const int slice = half*4 + wave;         // 0..7, ascending key ranges
  const int sbase = half*2048 + wave*512;  // A:[sbase,+256)  B:[sbase+256,+256)

  float ax, ay, az, bx, by, bz;
  {
    int ja = sbase + lane, jb = ja + 256;
    ax=sx[ja*3+0]; ay=sx[ja*3+1]; az=sx[ja*3+2];
    bx=sx[jb*3+0]; by=sx[jb*3+1]; bz=sx[jb*3+2];
  }
  {
    float assv = __fadd_rn(__fadd_rn(__fmul_rn(ax,ax), __fmul_rn(ay,ay)), __fmul_rn(az,az));
    float bssv = __fadd_rn(__fadd_rn(__fmul_rn(bx,bx), __fmul_rn(by,by)), __fmul_rn(bz,bz));
    cb[wave][0][0][lane] = make_float4(ax, bx, ay, by);
    cb[wave][0][1][lane] = make_float4(az, bz, assv, bssv);
  }

  float dA0=3.4e38f,dA1=3.4e38f,dA2=3.4e38f; int iA0=0,iA1=0,iA2=0;
  float dB0=3.4e38f,dB1=3.4e38f,dB2=3.4e38f; int iB0=0,iB1=0,iB2=0;

  int cur = 0;
  for (int c = 0; c < 4; ++c){
    if (c < 3){                          // next chunk's loads EARLY
      int ja = sbase + (c+1)*64 + lane, jb = ja + 256;
      ax=sx[ja*3+0]; ay=sx[ja*3+1]; az=sx[ja*3+2];
      bx=sx[jb*3+0]; by=sx[jb*3+1]; bz=sx[jb*3+2];
    }
    const int base = sbase + c*64;       // chain-A index base this chunk
    #pragma unroll 8
    for (int i = 0; i < 64; ++i){
      float4 lo = cb[wave][cur][0][i];   // broadcast ds_read_b128
      float4 hi = cb[wave][cur][1][i];
      f32x2 kx  = {lo.x, lo.y};
      f32x2 ky  = {lo.z, lo.w};
      f32x2 kz  = {hi.x, hi.y};
      f32x2 kss = {hi.z, hi.w};
      f32x2 dot, dd;
      // dist: dd = fma(-2, dot, qq+ss), dot = fma(z,fma(y,mul(x))) — packed
      asm("v_pk_mul_f32 %0, %2, %6\n\t"
          "v_pk_fma_f32 %0, %3, %7, %0\n\t"
          "v_pk_fma_f32 %0, %4, %8, %0\n\t"
          "v_pk_add_f32 %1, %9, %5\n\t"
          "v_pk_fma_f32 %1, %10, %0, %1"
          : "=&v"(dot), "=&v"(dd)
          : "v"(kx), "v"(ky), "v"(kz), "v"(kss),
            "v"(px2), "v"(py2), "v"(pz2), "v"(qq2), "v"(m2));
      const float ddA = dd.x, ddB = dd.y;
      {
        unsigned long long c0, c1, c2; int t;
        asm("v_cmp_lt_f32 %[c0], %[dd], %[d0]\n\t"
            "v_cmp_lt_f32 %[c1], %[dd], %[d1]\n\t"
            "v_cmp_lt_f32 %[c2], %[dd], %[d2]\n\t"
            "v_med3_f32 %[d2], %[dd], %[d1], %[d2]\n\t"
            "v_med3_f32 %[d1], %[dd], %[d0], %[d1]\n\t"
            "v_min_f32  %[d0], %[dd], %[d0]\n\t"
            "v_cndmask_b32 %[t], %[idx], %[i1], %[c1]\n\t"
            "v_cndmask_b32 %[i2], %[i2], %[t], %[c2]\n\t"
            "v_cndmask_b32 %[t], %[idx], %[i0], %[c0]\n\t"
            "v_cndmask_b32 %[i1], %[i1], %[t], %[c1]\n\t"
            "v_cndmask_b32 %[i0], %[i0], %[idx], %[c0]"
            : [d0]"+v"(dA0), [d1]"+v"(dA1), [d2]"+v"(dA2),
              [i0]"+v"(iA0), [i1]"+v"(iA1), [i2]"+v"(iA2),
              [t]"=&v"(t), [c0]"=&s"(c0), [c1]"=&s"(c1), [c2]"=&s"(c2)
            : [dd]"v"(ddA), [idx]"v"(base + i));
      }
      {
        unsigned long long c0, c1, c2; int t;
        asm("v_cmp_lt_f32 %[c0], %[dd], %[d0]\n\t"
            "v_cmp_lt_f32 %[c1], %[dd], %[d1]\n\t"
            "v_cmp_lt_f32 %[c2], %[dd], %[d2]\n\t"
            "v_med3_f32 %[d2], %[dd], %[d1], %[d2]\n\t"
            "v_med3_f32 %[d1], %[dd], %[d0], %[d1]\n\t"
            "v_min_f32  %[d0], %[dd], %[d0]\n\t"
            "v_cndmask_b32 %[t], %[idx], %[i1], %[c1]\n\t"
            "v_cndmask_b32 %[i2], %[i2], %[t], %[c2]\n\t"
            "v_cndmask_b32 %[t], %[idx], %[i0], %[c0]\n\t"
            "v_cndmask_b32 %[i1], %[i1], %[t], %[c1]\n\t"
            "v_cndmask_b32 %[i0], %[i0], %[idx], %[c0]"
            : [d0]"+v"(dB0), [d1]"+v"(dB1), [d2]"+v"(dB2),
              [i0]"+v"(iB0), [i1]"+v"(iB1), [i2]"+v"(iB2),
              [t]"=&v"(t), [c0]"=&s"(c0), [c1]"=&s"(c1), [c2]"=&s"(c2)
            : [dd]"v"(ddB), [idx]"v"(base + i + 256));
      }
    }
    if (c < 3){                          // write next chunk AFTER the scan
      int nxt = cur ^ 1;
      float assv = __fadd_rn(__fadd_rn(__fmul_rn(ax,ax), __fmul_rn(ay,ay)), __fmul_rn(az,az));
      float bssv = __fadd_rn(__fadd_rn(__fmul_rn(bx,bx), __fmul_rn(by,by)), __fmul_rn(bz,bz));
      cb[wave][nxt][0][lane] = make_float4(ax, bx, ay, by);
      cb[wave][nxt][1][lane] = make_float4(az, bz, assv, bssv);
      cur = nxt;
    }
  }

  // merge B into A (A indices < B indices -> strict '<' correct), write partial
  top3_insert(dB0, iB0, dA0,dA1,dA2, iA0,iA1,iA2);
  top3_insert(dB1, iB1, dA0,dA1,dA2, iA0,iA1,iA2);
  top3_insert(dB2, iB2, dA0,dA1,dA2, iA0,iA1,iA2);
  PD[(slice*3+0)*MTOT + gq] = dA0;
  PD[(slice*3+1)*MTOT + gq] = dA1;
  PD[(slice*3+2)*MTOT + gq] = dA2;
  PI[(slice*3+0)*MTOT + gq] = iA0;
  PI[(slice*3+1)*MTOT + gq] = iA1;
  PI[(slice*3+2)*MTOT + gq] = iA2;
}

// merge 8 slice-partials per query (ascending slice = ascending key range,
// strict '<' => reference top_k tie-break), compute weights, write kw/ki.
__global__ __launch_bounds__(256) void knnmerge_kernel(
    const float* __restrict__ PD, const int* __restrict__ PI,
    float* __restrict__ kw, int* __restrict__ ki)
{
  const int gq = blockIdx.x*256 + threadIdx.x;   // 0..65535
  float e0=3.4e38f, e1=3.4e38f, e2=3.4e38f;
  int   j0=0, j1=0, j2=0;
  #pragma unroll
  for (int s = 0; s < 8; ++s){
    #pragma unroll
    for (int j = 0; j < 3; ++j){
      float d = PD[(s*3+j)*MTOT + gq];
      int   i = PI[(s*3+j)*MTOT + gq];
      top3_insert(d, i, e0,e1,e2, j0,j1,j2);
    }
  }
  float wa = 1.0f/(e0+1e-8f), wb = 1.0f/(e1+1e-8f), wc = 1.0f/(e2+1e-8f);
  float sm = __fadd_rn(__fadd_rn(wa, wb), wc);
  size_t base = (size_t)gq*3;
  kw[base+0] = wa/sm; kw[base+1] = wb/sm; kw[base+2] = wc/sm;
  ki[base+0] = j0;    ki[base+1] = j1;    ki[base+2] = j2;
}

// ------------- fp32 -> bf16 weight conversion -------------
__global__ __launch_bounds__(256) void cvtw_kernel(
    const float* __restrict__ w0, const float* __restrict__ w1,
    unsigned short* __restrict__ w0b, unsigned short* __restrict__ w1b)
{
  int i = blockIdx.x*256 + threadIdx.x;
  if (i < 256*384) w0b[i] = f2bf(w0[i]);
  int j = i - 256*384;
  if (j >= 0 && j < 256*256) w1b[j] = f2bf(w1[j]);
}

// ------------- GEMM: Y[M][256] = A[M][KDIM] @ W[256][KDIM]^T + bias ----------
// BM=128, BN=256 (full), BK=64. 4 waves, wave w owns cols [w*64, w*64+64).
// AFUSE (gemm0): A is NOT materialized — staged on the fly:
//   k <  128: A[m][k]    = f2bf(ofeat[m][k])
//   k >= 128: A[m][k]    = f2bf(fma(w2,s2, fma(w1,s1, mul(w0,s0))))   (interp)
// with per-row kw/ki preloaded to LDS (exact same expressions as the old
// interp kernel -> bit-identical A bits). BNRELU (gemm1): BN0 scale/shift
// computed in-kernel from gemm0 stats, A' = relu(A*sc+sh) during staging.
// Epilogue: bf16 store + per-channel sum/sumsq atomics for BN stats.
template<int KDIM, bool BNRELU, bool AFUSE>
__global__ __launch_bounds__(256) void gemm_kernel(
    const unsigned short* __restrict__ A,
    const unsigned short* __restrict__ W,
    const float* __restrict__ bias,
    const float* __restrict__ s0sum,
    const float* __restrict__ s0sq,
    const float* __restrict__ bng,
    const float* __restrict__ bnbt,
    const float* __restrict__ kwg,
    const int*   __restrict__ kig,
    const float* __restrict__ sfeat,
    const float* __restrict__ ofeat,
    unsigned short* __restrict__ Y,
    float* __restrict__ osum,
    float* __restrict__ osq)
{
  __shared__ unsigned short As[128*64];   // 16 KB, XOR-swizzled 16B chunks
  __shared__ unsigned short Bs[256*64];   // 32 KB
  __shared__ float lsc[256], lsh[256];    // BNRELU only
  __shared__ float lkw[128][3];           // AFUSE only
  __shared__ int   lki[128][3];
  const int tid  = threadIdx.x;
  const int lane = tid & 63;
  const int wave = tid >> 6;
  const size_t mbase = (size_t)blockIdx.x * 128;
  if constexpr (BNRELU){
    float mean = s0sum[tid] * (1.0f/65536.0f);
    float var  = s0sq[tid] * (1.0f/65536.0f) - mean*mean;
    float s = bng[tid] / sqrtf(var + 1e-5f);
    lsc[tid] = s;
    lsh[tid] = __fmaf_rn(-mean, s, bnbt[tid]);
  }
  if constexpr (AFUSE){
    float* lkwf = &lkw[0][0];
    int*   lkif = &lki[0][0];
    for (int t = tid; t < 384; t += 256){
      lkwf[t] = kwg[mbase*3 + t];
      lkif[t] = kig[mbase*3 + t];
    }
  }
  f32x4 acc[8][4];
  #pragma unroll
  for (int m2 = 0; m2 < 8; ++m2)
    #pragma unroll
    for (int n2 = 0; n2 < 4; ++n2) acc[m2][n2] = f32x4{0.f,0.f,0.f,0.f};
  __syncthreads();

  for (int k0 = 0; k0 < KDIM; k0 += 64){
    if (k0) __syncthreads();
    // stage A: 128 rows x 8 chunks(16B) = 1024 chunks, 4/thread
    #pragma unroll
    for (int i = 0; i < 4; ++i){
      int cid = tid + 256*i;
      int row = cid >> 3, c8 = cid & 7;
      short8 v;
      if constexpr (AFUSE){
        const int m = (int)mbase + row;
        const int k = k0 + c8*8;
        float vals[8];
        if (k < COn){
          const float4* p = reinterpret_cast<const float4*>(ofeat + (size_t)m*COn + k);
          float4 u0 = p[0], u1 = p[1];
          vals[0]=u0.x; vals[1]=u0.y; vals[2]=u0.z; vals[3]=u0.w;
          vals[4]=u1.x; vals[5]=u1.y; vals[6]=u1.z; vals[7]=u1.w;
        } else {
          const int cc = k - COn;
          const int bb = m >> 14;
          const float* sb = sfeat + (size_t)bb*Sn*CSn;
          const float w0v = lkw[row][0], w1v = lkw[row][1], w2v = lkw[row][2];
          const int   i0  = lki[row][0], i1  = lki[row][1], i2  = lki[row][2];
          const float4* p0 = reinterpret_cast<const float4*>(sb + (size_t)i0*CSn + cc);
          const float4* p1 = reinterpret_cast<const float4*>(sb + (size_t)i1*CSn + cc);
          const float4* p2 = reinterpret_cast<const float4*>(sb + (size_t)i2*CSn + cc);
          float4 a0 = p0[0], a1 = p0[1];
          float4 b0v = p1[0], b1v = p1[1];
          float4 c0v = p2[0], c1v = p2[1];
          float s0[8] = {a0.x,a0.y,a0.z,a0.w,a1.x,a1.y,a1.z,a1.w};
          float s1[8] = {b0v.x,b0v.y,b0v.z,b0v.w,b1v.x,b1v.y,b1v.z,b1v.w};
          float s2[8] = {c0v.x,c0v.y,c0v.z,c0v.w,c1v.x,c1v.y,c1v.z,c1v.w};
          #pragma unroll
          for (int j = 0; j < 8; ++j)
            vals[j] = __fmaf_rn(w2v, s2[j], __fmaf_rn(w1v, s1[j], __fmul_rn(w0v, s0[j])));
        }
        #pragma unroll
        for (int j = 0; j < 8; ++j) v[j] = (short)f2bf(vals[j]);
      } else {
        v = *reinterpret_cast<const short8*>(A + (mbase+row)*KDIM + k0 + c8*8);
        if constexpr (BNRELU){
          #pragma unroll
          for (int j = 0; j < 8; ++j){
            int kc = k0 + c8*8 + j;
            float f = bf2f((unsigned short)v[j]);
            f = fmaxf(__fmaf_rn(f, lsc[kc], lsh[kc]), 0.0f);
            v[j] = (short)f2bf(f);
          }
        }
      }
      *reinterpret_cast<short8*>(reinterpret_cast<char*>(As) + row*128 + ((c8 ^ (row&7)) << 4)) = v;
    }
    // stage B (weights): 256 rows x 8 chunks = 2048 chunks, 8/thread
    #pragma unroll
    for (int i = 0; i < 8; ++i){
      int cid = tid + 256*i;
      int row = cid >> 3, c8 = cid & 7;
      short8 v = *reinterpret_cast<const short8*>(W + (size_t)row*KDIM + k0 + c8*8);
      *reinterpret_cast<short8*>(reinterpret_cast<char*>(Bs) + row*128 + ((c8 ^ (row&7)) << 4)) = v;
    }
    __syncthreads();
    #pragma unroll
    for (int kk = 0; kk < 2; ++kk){
      short8 af[8], bv[4];
      #pragma unroll
      for (int m2 = 0; m2 < 8; ++m2){
        int row = m2*16 + (lane & 15);
        int c8  = kk*4 + (lane >> 4);
        af[m2] = *reinterpret_cast<const short8*>(reinterpret_cast<char*>(As) + row*128 + ((c8 ^ (row&7)) << 4));
      }
      #pragma unroll
      for (int n2 = 0; n2 < 4; ++n2){
        int row = wave*64 + n2*16 + (lane & 15);
        int c8  = kk*4 + (lane >> 4);
        bv[n2] = *reinterpret_cast<const short8*>(reinterpret_cast<char*>(Bs) + row*128 + ((c8 ^ (row&7)) << 4));
      }
      #pragma unroll
      for (int m2 = 0; m2 < 8; ++m2)
        #pragma unroll
        for (int n2 = 0; n2 < 4; ++n2)
          acc[m2][n2] = __builtin_amdgcn_mfma_f32_16x16x32_bf16(af[m2], bv[n2], acc[m2][n2], 0, 0, 0);
    }
  }

  // epilogue: C/D layout col = lane&15, row = (lane>>4)*4 + j  [m89-verified]
  const int colg0 = wave*64;
  float spart[4] = {0,0,0,0}, qpart[4] = {0,0,0,0};
  #pragma unroll
  for (int m2 = 0; m2 < 8; ++m2){
    #pragma unroll
    for (int n2 = 0; n2 < 4; ++n2){
      const int gc  = colg0 + n2*16 + (lane & 15);
      const float bvv = bias[gc];
      #pragma unroll
      for (int j = 0; j < 4; ++j){
        float yv = acc[m2][n2][j] + bvv;
        size_t gr = mbase + m2*16 + (lane>>4)*4 + j;
        Y[gr*256 + gc] = f2bf(yv);
        spart[n2] += yv;
        qpart[n2] = __fmaf_rn(yv, yv, qpart[n2]);
      }
    }
  }
  #pragma unroll
  for (int n2 = 0; n2 < 4; ++n2){
    float s = spart[n2], q = qpart[n2];
    s += __shfl_xor(s, 16); q += __shfl_xor(q, 16);
    s += __shfl_xor(s, 32); q += __shfl_xor(q, 32);
    if (lane < 16){
      int gc = colg0 + n2*16 + lane;
      atomicAdd(&osum[gc], s);
      atomicAdd(&osq[gc], q);
    }
  }
}

// ------------- final BN1 + ReLU -> fp32 out (BN finalize folded in) -------------
__global__ __launch_bounds__(256) void apply_kernel(
    const unsigned short* __restrict__ y,
    const float* __restrict__ s1sum, const float* __restrict__ s1sq,
    const float* __restrict__ g, const float* __restrict__ bt,
    float* __restrict__ out)
{
  __shared__ float ssc[256], ssh[256];
  {
    int c = threadIdx.x;
    float mean = s1sum[c] * (1.0f/65536.0f);
    float var  = s1sq[c] * (1.0f/65536.0f) - mean*mean;
    float s = g[c] / sqrtf(var + 1e-5f);
    ssc[c] = s;
    ssh[c] = __fmaf_rn(-mean, s, bt[c]);
  }
  __syncthreads();
  const int t = blockIdx.x*256 + threadIdx.x;
  const size_t base = (size_t)t * 8;
  const int c0 = (int)(base & 255);
  short8 v = *reinterpret_cast<const short8*>(y + base);
  float r[8];
  #pragma unroll
  for (int j = 0; j < 8; ++j){
    float f = bf2f((unsigned short)v[j]);
    f = __fmaf_rn(f, ssc[c0+j], ssh[c0+j]);
    r[j] = fmaxf(f, 0.0f);
  }
  float4 o0, o1;
  o0.x=r[0]; o0.y=r[1]; o0.z=r[2]; o0.w=r[3];
  o1.x=r[4]; o1.y=r[5]; o1.z=r[6]; o1.w=r[7];
  *reinterpret_cast<float4*>(out + base)     = o0;
  *reinterpret_cast<float4*>(out + base + 4) = o1;
}

// ---------------- workspace layout ----------------
constexpr size_t WS_STATS = 0;                                  // 4*256 f32
constexpr size_t WS_W0B   = 8192;                               // 98304 bf16
constexpr size_t WS_W1B   = WS_W0B + 196608;                    // 65536 bf16
constexpr size_t WS_KW    = WS_W1B + 131072;                    // M*3 f32
constexpr size_t WS_KI    = WS_KW + 786432;                     // M*3 i32
constexpr size_t WS_BIG   = 4194304;                            // big region
constexpr size_t WS_Y0    = WS_BIG + (size_t)MTOT*CINn*2;       // M*256 bf16
// PD/PI (6.3 MB each) live at the start of the big region; they are dead
// after knnmerge. Y1 reuses the same region (written by gemm1, later).
constexpr size_t WS_PD    = WS_BIG;
constexpr size_t WS_PI    = WS_BIG + (size_t)8*3*MTOT*4;

extern "C" void kernel_launch(void* const* d_in, const int* in_sizes, int n_in,
                              void* d_out, int out_size, void* d_ws, size_t ws_size,
                              hipStream_t stream)
{
  const float* sxyz  = (const float*)d_in[0];
  const float* sfeat = (const float*)d_in[1];
  const float* oxyz  = (const float*)d_in[2];
  const float* ofeat = (const float*)d_in[3];
  const float* w0    = (const float*)d_in[4];
  const float* b0    = (const float*)d_in[5];
  const float* g0    = (const float*)d_in[6];
  const float* bt0   = (const float*)d_in[7];
  const float* w1    = (const float*)d_in[8];
  const float* b1    = (const float*)d_in[9];
  const float* g1    = (const float*)d_in[10];
  const float* bt1   = (const float*)d_in[11];
  // d_in[12] = k (always 3, hard-coded)

  char* ws = (char*)d_ws;
  float* stats  = (float*)(ws + WS_STATS);   // sum0,ssq0,sum1,ssq1
  unsigned short* w0b = (unsigned short*)(ws + WS_W0B);
  unsigned short* w1b = (unsigned short*)(ws + WS_W1B);
  float* kw = (float*)(ws + WS_KW);
  int*   ki = (int*)(ws + WS_KI);
  float* PD = (float*)(ws + WS_PD);
  int*   PI = (int*)(ws + WS_PI);
  unsigned short* Y0 = (unsigned short*)(ws + WS_Y0);
  unsigned short* Y1 = (unsigned short*)(ws + WS_BIG);   // reuse (PD/PI dead)

  hipMemsetAsync(stats, 0, 4*256*sizeof(float), stream);
  cvtw_kernel<<<640, 256, 0, stream>>>(w0, w1, w0b, w1b);
  knn_kernel<<<2048, 256, 0, stream>>>(sxyz, oxyz, PD, PI);
  knnmerge_kernel<<<MTOT/256, 256, 0, stream>>>(PD, PI, kw, ki);
  gemm_kernel<CINn, false, true><<<MTOT/128, 256, 0, stream>>>(
      nullptr, w0b, b0, nullptr, nullptr, nullptr, nullptr,
      kw, ki, sfeat, ofeat, Y0, stats, stats + 256);
  gemm_kernel<256, true, false><<<MTOT/128, 256, 0, stream>>>(
      Y0, w1b, b1, stats, stats + 256, g0, bt0,
      nullptr, nullptr, nullptr, nullptr, Y1, stats + 512, stats + 768);
  apply_kernel<<<(MTOT*256)/(256*8), 256, 0, stream>>>(
      Y1, stats + 512, stats + 768, g1, bt1, (float*)d_out);
}

// Round 12
// 222.034 us; speedup vs baseline: 1.2495x; 1.0828x over previous
//
#include <hip/hip_runtime.h>
#include <hip/hip_bf16.h>
#include <cstdint>
#include <cstddef>

// Problem constants (fixed shapes)
#define Bn   4
#define Sn   4096
#define Nn   16384
#define CSn  256
#define COn  128
#define CINn 384
#define MTOT 65536   // B*N

using short8 = short __attribute__((ext_vector_type(8)));
using f32x4  = float __attribute__((ext_vector_type(4)));

static __device__ __forceinline__ float bf2f(unsigned short u){
  unsigned int x = ((unsigned int)u) << 16;
  return __builtin_bit_cast(float, x);
}
static __device__ __forceinline__ unsigned short f2bf(float f){
  unsigned int x = __builtin_bit_cast(unsigned int, f);
  x += 0x7fffu + ((x >> 16) & 1u);   // RNE
  return (unsigned short)(x >> 16);
}

// ---------------- KNN ----------------
// branchy insert used only in tiny merges (sorted-triple inputs)
static __device__ __forceinline__ void top3_insert(float d, int s,
    float& d0, float& d1, float& d2, int& i0, int& i1, int& i2){
  if (d < d2){
    if (d < d1){
      d2 = d1; i2 = i1;
      if (d < d0){ d1 = d0; i1 = i0; d0 = d; i0 = s; }
      else       { d1 = d;  i1 = s; }
    } else { d2 = d; i2 = s; }
  }
}

// 2048 blocks x 256 threads (4 waves), fully wave-independent (NO barriers).
// Block = 64 queries (lane = query) x one S-half; wave w scans a SINGLE
// 512-key chain [half*2048 + w*512, +512) in ascending order. Keys staged
// per-wave into double-buffered LDS chunks of 64 float4 {x,y,z,ss} (16B
// lane-contiguous writes = conflict-free; scan reads are wave-uniform
// ds_read_b128 broadcast). Inner loop: ONE asm block per key (16 instrs),
// scalar dist (bit-identical to reference chain: fma(-2, fma(z,fma(y,mul(x))),
// qq+ss)) + branch-free top3 (cmp/med3/min/cndmask, strict '<').
// Single chain removes all f32x2 pack/unpack glue that cost R10/R11 ~2x.
// Wave writes top-3 partial to PD/PI[slice]; knnmerge merges 8 slices
// ascending -> reference top_k tie-break exact.
__global__ __launch_bounds__(256) void knn_kernel(
    const float* __restrict__ sxyz, const float* __restrict__ oxyz,
    float* __restrict__ PD, int* __restrict__ PI)
{
  __shared__ float4 cb[4][2][64];   // 8 KB: [wave][dbuf][key]

  const int b    = blockIdx.x >> 9;        // 512 blocks per batch
  const int qblk = (blockIdx.x >> 1) & 255;
  const int half = blockIdx.x & 1;
  const int lane = threadIdx.x & 63;
  const int wave = threadIdx.x >> 6;
  const int gq   = b*Nn + qblk*64 + lane;  // global query id [0,65536)
  const float* op = oxyz + (size_t)gq*3;
  const float px = op[0], py = op[1], pz = op[2];
  const float qq = __fadd_rn(__fadd_rn(__fmul_rn(px,px), __fmul_rn(py,py)), __fmul_rn(pz,pz));

  const float* sx = sxyz + (size_t)b*Sn*3;
  const int slice = half*4 + wave;         // 0..7, ascending key ranges
  const int sbase = half*2048 + wave*512;  // this wave's 512-key chain

  float ax, ay, az;
  {
    int j = sbase + lane;
    ax=sx[j*3+0]; ay=sx[j*3+1]; az=sx[j*3+2];
  }
  {
    float ssv = __fadd_rn(__fadd_rn(__fmul_rn(ax,ax), __fmul_rn(ay,ay)), __fmul_rn(az,az));
    cb[wave][0][lane] = make_float4(ax, ay, az, ssv);
  }

  float d0=3.4e38f, d1=3.4e38f, d2=3.4e38f;
  int   i0=0, i1=0, i2=0;

  int cur = 0;
  for (int c = 0; c < 8; ++c){
    if (c < 7){                          // next chunk's loads EARLY
      int j = sbase + (c+1)*64 + lane;
      ax=sx[j*3+0]; ay=sx[j*3+1]; az=sx[j*3+2];
    }
    const int base = sbase + c*64;
    #pragma unroll 8
    for (int i = 0; i < 64; ++i){
      float4 k = cb[wave][cur][i];       // broadcast ds_read_b128
      float t, u; int t2;
      unsigned long long c0, c1, c2;
      asm("v_mul_f32 %[t], %[kx], %[px]\n\t"
          "v_fma_f32 %[t], %[ky], %[py], %[t]\n\t"
          "v_fma_f32 %[t], %[kz], %[pz], %[t]\n\t"
          "v_add_f32 %[u], %[qq], %[ss]\n\t"
          "v_fma_f32 %[u], -2.0, %[t], %[u]\n\t"
          "v_cmp_lt_f32 %[c0], %[u], %[d0]\n\t"
          "v_cmp_lt_f32 %[c1], %[u], %[d1]\n\t"
          "v_cmp_lt_f32 %[c2], %[u], %[d2]\n\t"
          "v_med3_f32 %[d2], %[u], %[d1], %[d2]\n\t"
          "v_med3_f32 %[d1], %[u], %[d0], %[d1]\n\t"
          "v_min_f32  %[d0], %[u], %[d0]\n\t"
          "v_cndmask_b32 %[t2], %[idx], %[i1], %[c1]\n\t"
          "v_cndmask_b32 %[i2], %[i2], %[t2], %[c2]\n\t"
          "v_cndmask_b32 %[t2], %[idx], %[i0], %[c0]\n\t"
          "v_cndmask_b32 %[i1], %[i1], %[t2], %[c1]\n\t"
          "v_cndmask_b32 %[i0], %[i0], %[idx], %[c0]"
          : [d0]"+v"(d0), [d1]"+v"(d1), [d2]"+v"(d2),
            [i0]"+v"(i0), [i1]"+v"(i1), [i2]"+v"(i2),
            [t]"=&v"(t), [u]"=&v"(u), [t2]"=&v"(t2),
            [c0]"=&s"(c0), [c1]"=&s"(c1), [c2]"=&s"(c2)
          : [kx]"v"(k.x), [ky]"v"(k.y), [kz]"v"(k.z), [ss]"v"(k.w),
            [px]"v"(px), [py]"v"(py), [pz]"v"(pz), [qq]"v"(qq),
            [idx]"v"(base + i));
    }
    if (c < 7){                          // write next chunk AFTER the scan
      int nxt = cur ^ 1;
      float ssv = __fadd_rn(__fadd_rn(__fmul_rn(ax,ax), __fmul_rn(ay,ay)), __fmul_rn(az,az));
      cb[wave][nxt][lane] = make_float4(ax, ay, az, ssv);
      cur = nxt;
    }
  }

  PD[(slice*3+0)*MTOT + gq] = d0;
  PD[(slice*3+1)*MTOT + gq] = d1;
  PD[(slice*3+2)*MTOT + gq] = d2;
  PI[(slice*3+0)*MTOT + gq] = i0;
  PI[(slice*3+1)*MTOT + gq] = i1;
  PI[(slice*3+2)*MTOT + gq] = i2;
}

// merge 8 slice-partials per query (ascending slice = ascending key range,
// strict '<' => reference top_k tie-break), compute weights, write kw/ki.
__global__ __launch_bounds__(256) void knnmerge_kernel(
    const float* __restrict__ PD, const int* __restrict__ PI,
    float* __restrict__ kw, int* __restrict__ ki)
{
  const int gq = blockIdx.x*256 + threadIdx.x;   // 0..65535
  float e0=3.4e38f, e1=3.4e38f, e2=3.4e38f;
  int   j0=0, j1=0, j2=0;
  #pragma unroll
  for (int s = 0; s < 8; ++s){
    #pragma unroll
    for (int j = 0; j < 3; ++j){
      float d = PD[(s*3+j)*MTOT + gq];
      int   i = PI[(s*3+j)*MTOT + gq];
      top3_insert(d, i, e0,e1,e2, j0,j1,j2);
    }
  }
  float wa = 1.0f/(e0+1e-8f), wb = 1.0f/(e1+1e-8f), wc = 1.0f/(e2+1e-8f);
  float sm = __fadd_rn(__fadd_rn(wa, wb), wc);
  size_t base = (size_t)gq*3;
  kw[base+0] = wa/sm; kw[base+1] = wb/sm; kw[base+2] = wc/sm;
  ki[base+0] = j0;    ki[base+1] = j1;    ki[base+2] = j2;
}

// ------------- fp32 -> bf16 weight conversion -------------
__global__ __launch_bounds__(256) void cvtw_kernel(
    const float* __restrict__ w0, const float* __restrict__ w1,
    unsigned short* __restrict__ w0b, unsigned short* __restrict__ w1b)
{
  int i = blockIdx.x*256 + threadIdx.x;
  if (i < 256*384) w0b[i] = f2bf(w0[i]);
  int j = i - 256*384;
  if (j >= 0 && j < 256*256) w1b[j] = f2bf(w1[j]);
}

// ------------- GEMM: Y[M][256] = A[M][KDIM] @ W[256][KDIM]^T + bias ----------
// BM=128, BN=256 (full), BK=64. 4 waves, wave w owns cols [w*64, w*64+64).
// AFUSE (gemm0): A is NOT materialized — staged on the fly:
//   k <  128: A[m][k]    = f2bf(ofeat[m][k])
//   k >= 128: A[m][k]    = f2bf(fma(w2,s2, fma(w1,s1, mul(w0,s0))))   (interp)
// with per-row kw/ki preloaded to LDS (exact same expressions as the old
// interp kernel -> bit-identical A bits). BNRELU (gemm1): BN0 scale/shift
// computed in-kernel from gemm0 stats, A' = relu(A*sc+sh) during staging.
// Epilogue: bf16 store + per-channel sum/sumsq atomics for BN stats.
template<int KDIM, bool BNRELU, bool AFUSE>
__global__ __launch_bounds__(256) void gemm_kernel(
    const unsigned short* __restrict__ A,
    const unsigned short* __restrict__ W,
    const float* __restrict__ bias,
    const float* __restrict__ s0sum,
    const float* __restrict__ s0sq,
    const float* __restrict__ bng,
    const float* __restrict__ bnbt,
    const float* __restrict__ kwg,
    const int*   __restrict__ kig,
    const float* __restrict__ sfeat,
    const float* __restrict__ ofeat,
    unsigned short* __restrict__ Y,
    float* __restrict__ osum,
    float* __restrict__ osq)
{
  __shared__ unsigned short As[128*64];   // 16 KB, XOR-swizzled 16B chunks
  __shared__ unsigned short Bs[256*64];   // 32 KB
  __shared__ float lsc[256], lsh[256];    // BNRELU only
  __shared__ float lkw[128][3];           // AFUSE only
  __shared__ int   lki[128][3];
  const int tid  = threadIdx.x;
  const int lane = tid & 63;
  const int wave = tid >> 6;
  const size_t mbase = (size_t)blockIdx.x * 128;
  if constexpr (BNRELU){
    float mean = s0sum[tid] * (1.0f/65536.0f);
    float var  = s0sq[tid] * (1.0f/65536.0f) - mean*mean;
    float s = bng[tid] / sqrtf(var + 1e-5f);
    lsc[tid] = s;
    lsh[tid] = __fmaf_rn(-mean, s, bnbt[tid]);
  }
  if constexpr (AFUSE){
    float* lkwf = &lkw[0][0];
    int*   lkif = &lki[0][0];
    for (int t = tid; t < 384; t += 256){
      lkwf[t] = kwg[mbase*3 + t];
      lkif[t] = kig[mbase*3 + t];
    }
  }
  f32x4 acc[8][4];
  #pragma unroll
  for (int m2 = 0; m2 < 8; ++m2)
    #pragma unroll
    for (int n2 = 0; n2 < 4; ++n2) acc[m2][n2] = f32x4{0.f,0.f,0.f,0.f};
  __syncthreads();

  for (int k0 = 0; k0 < KDIM; k0 += 64){
    if (k0) __syncthreads();
    // stage A: 128 rows x 8 chunks(16B) = 1024 chunks, 4/thread
    #pragma unroll
    for (int i = 0; i < 4; ++i){
      int cid = tid + 256*i;
      int row = cid >> 3, c8 = cid & 7;
      short8 v;
      if constexpr (AFUSE){
        const int m = (int)mbase + row;
        const int k = k0 + c8*8;
        float vals[8];
        if (k < COn){
          const float4* p = reinterpret_cast<const float4*>(ofeat + (size_t)m*COn + k);
          float4 u0 = p[0], u1 = p[1];
          vals[0]=u0.x; vals[1]=u0.y; vals[2]=u0.z; vals[3]=u0.w;
          vals[4]=u1.x; vals[5]=u1.y; vals[6]=u1.z; vals[7]=u1.w;
        } else {
          const int cc = k - COn;
          const int bb = m >> 14;
          const float* sb = sfeat + (size_t)bb*Sn*CSn;
          const float w0v = lkw[row][0], w1v = lkw[row][1], w2v = lkw[row][2];
          const int   i0  = lki[row][0], i1  = lki[row][1], i2  = lki[row][2];
          const float4* p0 = reinterpret_cast<const float4*>(sb + (size_t)i0*CSn + cc);
          const float4* p1 = reinterpret_cast<const float4*>(sb + (size_t)i1*CSn + cc);
          const float4* p2 = reinterpret_cast<const float4*>(sb + (size_t)i2*CSn + cc);
          float4 a0 = p0[0], a1 = p0[1];
          float4 b0v = p1[0], b1v = p1[1];
          float4 c0v = p2[0], c1v = p2[1];
          float s0[8] = {a0.x,a0.y,a0.z,a0.w,a1.x,a1.y,a1.z,a1.w};
          float s1[8] = {b0v.x,b0v.y,b0v.z,b0v.w,b1v.x,b1v.y,b1v.z,b1v.w};
          float s2[8] = {c0v.x,c0v.y,c0v.z,c0v.w,c1v.x,c1v.y,c1v.z,c1v.w};
          #pragma unroll
          for (int j = 0; j < 8; ++j)
            vals[j] = __fmaf_rn(w2v, s2[j], __fmaf_rn(w1v, s1[j], __fmul_rn(w0v, s0[j])));
        }
        #pragma unroll
        for (int j = 0; j < 8; ++j) v[j] = (short)f2bf(vals[j]);
      } else {
        v = *reinterpret_cast<const short8*>(A + (mbase+row)*KDIM + k0 + c8*8);
        if constexpr (BNRELU){
          #pragma unroll
          for (int j = 0; j < 8; ++j){
            int kc = k0 + c8*8 + j;
            float f = bf2f((unsigned short)v[j]);
            f = fmaxf(__fmaf_rn(f, lsc[kc], lsh[kc]), 0.0f);
            v[j] = (short)f2bf(f);
          }
        }
      }
      *reinterpret_cast<short8*>(reinterpret_cast<char*>(As) + row*128 + ((c8 ^ (row&7)) << 4)) = v;
    }
    // stage B (weights): 256 rows x 8 chunks = 2048 chunks, 8/thread
    #pragma unroll
    for (int i = 0; i < 8; ++i){
      int cid = tid + 256*i;
      int row = cid >> 3, c8 = cid & 7;
      short8 v = *reinterpret_cast<const short8*>(W + (size_t)row*KDIM + k0 + c8*8);
      *reinterpret_cast<short8*>(reinterpret_cast<char*>(Bs) + row*128 + ((c8 ^ (row&7)) << 4)) = v;
    }
    __syncthreads();
    #pragma unroll
    for (int kk = 0; kk < 2; ++kk){
      short8 af[8], bv[4];
      #pragma unroll
      for (int m2 = 0; m2 < 8; ++m2){
        int row = m2*16 + (lane & 15);
        int c8  = kk*4 + (lane >> 4);
        af[m2] = *reinterpret_cast<const short8*>(reinterpret_cast<char*>(As) + row*128 + ((c8 ^ (row&7)) << 4));
      }
      #pragma unroll
      for (int n2 = 0; n2 < 4; ++n2){
        int row = wave*64 + n2*16 + (lane & 15);
        int c8  = kk*4 + (lane >> 4);
        bv[n2] = *reinterpret_cast<const short8*>(reinterpret_cast<char*>(Bs) + row*128 + ((c8 ^ (row&7)) << 4));
      }
      #pragma unroll
      for (int m2 = 0; m2 < 8; ++m2)
        #pragma unroll
        for (int n2 = 0; n2 < 4; ++n2)
          acc[m2][n2] = __builtin_amdgcn_mfma_f32_16x16x32_bf16(af[m2], bv[n2], acc[m2][n2], 0, 0, 0);
    }
  }

  // epilogue: C/D layout col = lane&15, row = (lane>>4)*4 + j  [m89-verified]
  const int colg0 = wave*64;
  float spart[4] = {0,0,0,0}, qpart[4] = {0,0,0,0};
  #pragma unroll
  for (int m2 = 0; m2 < 8; ++m2){
    #pragma unroll
    for (int n2 = 0; n2 < 4; ++n2){
      const int gc  = colg0 + n2*16 + (lane & 15);
      const float bvv = bias[gc];
      #pragma unroll
      for (int j = 0; j < 4; ++j){
        float yv = acc[m2][n2][j] + bvv;
        size_t gr = mbase + m2*16 + (lane>>4)*4 + j;
        Y[gr*256 + gc] = f2bf(yv);
        spart[n2] += yv;
        qpart[n2] = __fmaf_rn(yv, yv, qpart[n2]);
      }
    }
  }
  #pragma unroll
  for (int n2 = 0; n2 < 4; ++n2){
    float s = spart[n2], q = qpart[n2];
    s += __shfl_xor(s, 16); q += __shfl_xor(q, 16);
    s += __shfl_xor(s, 32); q += __shfl_xor(q, 32);
    if (lane < 16){
      int gc = colg0 + n2*16 + lane;
      atomicAdd(&osum[gc], s);
      atomicAdd(&osq[gc], q);
    }
  }
}

// ------------- final BN1 + ReLU -> fp32 out (BN finalize folded in) -------------
__global__ __launch_bounds__(256) void apply_kernel(
    const unsigned short* __restrict__ y,
    const float* __restrict__ s1sum, const float* __restrict__ s1sq,
    const float* __restrict__ g, const float* __restrict__ bt,
    float* __restrict__ out)
{
  __shared__ float ssc[256], ssh[256];
  {
    int c = threadIdx.x;
    float mean = s1sum[c] * (1.0f/65536.0f);
    float var  = s1sq[c] * (1.0f/65536.0f) - mean*mean;
    float s = g[c] / sqrtf(var + 1e-5f);
    ssc[c] = s;
    ssh[c] = __fmaf_rn(-mean, s, bt[c]);
  }
  __syncthreads();
  const int t = blockIdx.x*256 + threadIdx.x;
  const size_t base = (size_t)t * 8;
  const int c0 = (int)(base & 255);
  short8 v = *reinterpret_cast<const short8*>(y + base);
  float r[8];
  #pragma unroll
  for (int j = 0; j < 8; ++j){
    float f = bf2f((unsigned short)v[j]);
    f = __fmaf_rn(f, ssc[c0+j], ssh[c0+j]);
    r[j] = fmaxf(f, 0.0f);
  }
  float4 o0, o1;
  o0.x=r[0]; o0.y=r[1]; o0.z=r[2]; o0.w=r[3];
  o1.x=r[4]; o1.y=r[5]; o1.z=r[6]; o1.w=r[7];
  *reinterpret_cast<float4*>(out + base)     = o0;
  *reinterpret_cast<float4*>(out + base + 4) = o1;
}

// ---------------- workspace layout ----------------
constexpr size_t WS_STATS = 0;                                  // 4*256 f32
constexpr size_t WS_W0B   = 8192;                               // 98304 bf16
constexpr size_t WS_W1B   = WS_W0B + 196608;                    // 65536 bf16
constexpr size_t WS_KW    = WS_W1B + 131072;                    // M*3 f32
constexpr size_t WS_KI    = WS_KW + 786432;                     // M*3 i32
constexpr size_t WS_BIG   = 4194304;                            // big region
constexpr size_t WS_Y0    = WS_BIG + (size_t)MTOT*CINn*2;       // M*256 bf16
// PD/PI (6.3 MB each) live at the start of the big region; they are dead
// after knnmerge. Y1 reuses the same region (written by gemm1, later).
constexpr size_t WS_PD    = WS_BIG;
constexpr size_t WS_PI    = WS_BIG + (size_t)8*3*MTOT*4;

extern "C" void kernel_launch(void* const* d_in, const int* in_sizes, int n_in,
                              void* d_out, int out_size, void* d_ws, size_t ws_size,
                              hipStream_t stream)
{
  const float* sxyz  = (const float*)d_in[0];
  const float* sfeat = (const float*)d_in[1];
  const float* oxyz  = (const float*)d_in[2];
  const float* ofeat = (const float*)d_in[3];
  const float* w0    = (const float*)d_in[4];
  const float* b0    = (const float*)d_in[5];
  const float* g0    = (const float*)d_in[6];
  const float* bt0   = (const float*)d_in[7];
  const float* w1    = (const float*)d_in[8];
  const float* b1    = (const float*)d_in[9];
  const float* g1    = (const float*)d_in[10];
  const float* bt1   = (const float*)d_in[11];
  // d_in[12] = k (always 3, hard-coded)

  char* ws = (char*)d_ws;
  float* stats  = (float*)(ws + WS_STATS);   // sum0,ssq0,sum1,ssq1
  unsigned short* w0b = (unsigned short*)(ws + WS_W0B);
  unsigned short* w1b = (unsigned short*)(ws + WS_W1B);
  float* kw = (float*)(ws + WS_KW);
  int*   ki = (int*)(ws + WS_KI);
  float* PD = (float*)(ws + WS_PD);
  int*   PI = (int*)(ws + WS_PI);
  unsigned short* Y0 = (unsigned short*)(ws + WS_Y0);
  unsigned short* Y1 = (unsigned short*)(ws + WS_BIG);   // reuse (PD/PI dead)

  hipMemsetAsync(stats, 0, 4*256*sizeof(float), stream);
  cvtw_kernel<<<640, 256, 0, stream>>>(w0, w1, w0b, w1b);
  knn_kernel<<<2048, 256, 0, stream>>>(sxyz, oxyz, PD, PI);
  knnmerge_kernel<<<MTOT/256, 256, 0, stream>>>(PD, PI, kw, ki);
  gemm_kernel<CINn, false, true><<<MTOT/128, 256, 0, stream>>>(
      nullptr, w0b, b0, nullptr, nullptr, nullptr, nullptr,
      kw, ki, sfeat, ofeat, Y0, stats, stats + 256);
  gemm_kernel<256, true, false><<<MTOT/128, 256, 0, stream>>>(
      Y0, w1b, b1, stats, stats + 256, g0, bt0,
      nullptr, nullptr, nullptr, nullptr, Y1, stats + 512, stats + 768);
  apply_kernel<<<(MTOT*256)/(256*8), 256, 0, stream>>>(
      Y1, stats + 512, stats + 768, g1, bt1, (float*)d_out);
}

// Round 13
// 221.170 us; speedup vs baseline: 1.2544x; 1.0039x over previous
//
#include <hip/hip_runtime.h>
#include <hip/hip_bf16.h>
#include <cstdint>
#include <cstddef>

// Problem constants (fixed shapes)
#define Bn   4
#define Sn   4096
#define Nn   16384
#define CSn  256
#define COn  128
#define CINn 384
#define MTOT 65536   // B*N

using short8 = short __attribute__((ext_vector_type(8)));
using f32x4  = float __attribute__((ext_vector_type(4)));

static __device__ __forceinline__ float bf2f(unsigned short u){
  unsigned int x = ((unsigned int)u) << 16;
  return __builtin_bit_cast(float, x);
}
static __device__ __forceinline__ unsigned short f2bf(float f){
  unsigned int x = __builtin_bit_cast(unsigned int, f);
  x += 0x7fffu + ((x >> 16) & 1u);   // RNE
  return (unsigned short)(x >> 16);
}

// ---------------- KNN ----------------
// branchy insert used only in tiny merges (sorted-triple inputs)
static __device__ __forceinline__ void top3_insert(float d, int s,
    float& d0, float& d1, float& d2, int& i0, int& i1, int& i2){
  if (d < d2){
    if (d < d1){
      d2 = d1; i2 = i1;
      if (d < d0){ d1 = d0; i1 = i0; d0 = d; i0 = s; }
      else       { d1 = d;  i1 = s; }
    } else { d2 = d; i2 = s; }
  }
}

// 4096 blocks x 128 threads (2 waves), fully wave-independent (NO barriers).
// R12 inner loop kept verbatim (one 16-instr asm block per key; scalar dist
// bit-identical to reference; branch-free top3 strict '<'). Geometry change:
// 2-wave blocks x 4096 = 16 workgroups/CU x 2 waves = 32 waves/CU target
// (R12's 4-wave blocks sat at ~48% occupancy -> serial top3 dep chain had
// bubbles). Block = (query-group, slice-pair); wave w handles slice
// spair*2+w, keys [slice*512,(slice+1)*512) ascending. Partials to PD/PI;
// knnmerge merges 8 slices ascending -> reference top_k tie-break exact.
__global__ __launch_bounds__(128) void knn_kernel(
    const float* __restrict__ sxyz, const float* __restrict__ oxyz,
    float* __restrict__ PD, int* __restrict__ PI)
{
  __shared__ float4 cb[2][2][64];   // 4 KB: [wave][dbuf][key]

  const int b     = blockIdx.x >> 10;      // 1024 blocks per batch
  const int rem   = blockIdx.x & 1023;
  const int qblk  = rem >> 2;              // 0..255
  const int spair = rem & 3;               // 0..3
  const int lane  = threadIdx.x & 63;
  const int wave  = threadIdx.x >> 6;      // 0..1
  const int gq    = b*Nn + qblk*64 + lane; // global query id [0,65536)
  const float* op = oxyz + (size_t)gq*3;
  const float px = op[0], py = op[1], pz = op[2];
  const float qq = __fadd_rn(__fadd_rn(__fmul_rn(px,px), __fmul_rn(py,py)), __fmul_rn(pz,pz));

  const float* sx = sxyz + (size_t)b*Sn*3;
  const int slice = spair*2 + wave;        // 0..7, ascending key ranges
  const int sbase = slice*512;             // this wave's 512-key chain

  float ax, ay, az;
  {
    int j = sbase + lane;
    ax=sx[j*3+0]; ay=sx[j*3+1]; az=sx[j*3+2];
  }
  {
    float ssv = __fadd_rn(__fadd_rn(__fmul_rn(ax,ax), __fmul_rn(ay,ay)), __fmul_rn(az,az));
    cb[wave][0][lane] = make_float4(ax, ay, az, ssv);
  }

  float d0=3.4e38f, d1=3.4e38f, d2=3.4e38f;
  int   i0=0, i1=0, i2=0;

  int cur = 0;
  for (int c = 0; c < 8; ++c){
    if (c < 7){                          // next chunk's loads EARLY
      int j = sbase + (c+1)*64 + lane;
      ax=sx[j*3+0]; ay=sx[j*3+1]; az=sx[j*3+2];
    }
    const int base = sbase + c*64;
    #pragma unroll 8
    for (int i = 0; i < 64; ++i){
      float4 k = cb[wave][cur][i];       // broadcast ds_read_b128
      float t, u; int t2;
      unsigned long long c0, c1, c2;
      asm("v_mul_f32 %[t], %[kx], %[px]\n\t"
          "v_fma_f32 %[t], %[ky], %[py], %[t]\n\t"
          "v_fma_f32 %[t], %[kz], %[pz], %[t]\n\t"
          "v_add_f32 %[u], %[qq], %[ss]\n\t"
          "v_fma_f32 %[u], -2.0, %[t], %[u]\n\t"
          "v_cmp_lt_f32 %[c0], %[u], %[d0]\n\t"
          "v_cmp_lt_f32 %[c1], %[u], %[d1]\n\t"
          "v_cmp_lt_f32 %[c2], %[u], %[d2]\n\t"
          "v_med3_f32 %[d2], %[u], %[d1], %[d2]\n\t"
          "v_med3_f32 %[d1], %[u], %[d0], %[d1]\n\t"
          "v_min_f32  %[d0], %[u], %[d0]\n\t"
          "v_cndmask_b32 %[t2], %[idx], %[i1], %[c1]\n\t"
          "v_cndmask_b32 %[i2], %[i2], %[t2], %[c2]\n\t"
          "v_cndmask_b32 %[t2], %[idx], %[i0], %[c0]\n\t"
          "v_cndmask_b32 %[i1], %[i1], %[t2], %[c1]\n\t"
          "v_cndmask_b32 %[i0], %[i0], %[idx], %[c0]"
          : [d0]"+v"(d0), [d1]"+v"(d1), [d2]"+v"(d2),
            [i0]"+v"(i0), [i1]"+v"(i1), [i2]"+v"(i2),
            [t]"=&v"(t), [u]"=&v"(u), [t2]"=&v"(t2),
            [c0]"=&s"(c0), [c1]"=&s"(c1), [c2]"=&s"(c2)
          : [kx]"v"(k.x), [ky]"v"(k.y), [kz]"v"(k.z), [ss]"v"(k.w),
            [px]"v"(px), [py]"v"(py), [pz]"v"(pz), [qq]"v"(qq),
            [idx]"v"(base + i));
    }
    if (c < 7){                          // write next chunk AFTER the scan
      int nxt = cur ^ 1;
      float ssv = __fadd_rn(__fadd_rn(__fmul_rn(ax,ax), __fmul_rn(ay,ay)), __fmul_rn(az,az));
      cb[wave][nxt][lane] = make_float4(ax, ay, az, ssv);
      cur = nxt;
    }
  }

  PD[(slice*3+0)*MTOT + gq] = d0;
  PD[(slice*3+1)*MTOT + gq] = d1;
  PD[(slice*3+2)*MTOT + gq] = d2;
  PI[(slice*3+0)*MTOT + gq] = i0;
  PI[(slice*3+1)*MTOT + gq] = i1;
  PI[(slice*3+2)*MTOT + gq] = i2;
}

// merge 8 slice-partials per query (ascending slice = ascending key range,
// strict '<' => reference top_k tie-break), compute weights, write kw/ki.
__global__ __launch_bounds__(256) void knnmerge_kernel(
    const float* __restrict__ PD, const int* __restrict__ PI,
    float* __restrict__ kw, int* __restrict__ ki)
{
  const int gq = blockIdx.x*256 + threadIdx.x;   // 0..65535
  float e0=3.4e38f, e1=3.4e38f, e2=3.4e38f;
  int   j0=0, j1=0, j2=0;
  #pragma unroll
  for (int s = 0; s < 8; ++s){
    #pragma unroll
    for (int j = 0; j < 3; ++j){
      float d = PD[(s*3+j)*MTOT + gq];
      int   i = PI[(s*3+j)*MTOT + gq];
      top3_insert(d, i, e0,e1,e2, j0,j1,j2);
    }
  }
  float wa = 1.0f/(e0+1e-8f), wb = 1.0f/(e1+1e-8f), wc = 1.0f/(e2+1e-8f);
  float sm = __fadd_rn(__fadd_rn(wa, wb), wc);
  size_t base = (size_t)gq*3;
  kw[base+0] = wa/sm; kw[base+1] = wb/sm; kw[base+2] = wc/sm;
  ki[base+0] = j0;    ki[base+1] = j1;    ki[base+2] = j2;
}

// ------------- fp32 -> bf16 weight conversion -------------
__global__ __launch_bounds__(256) void cvtw_kernel(
    const float* __restrict__ w0, const float* __restrict__ w1,
    unsigned short* __restrict__ w0b, unsigned short* __restrict__ w1b)
{
  int i = blockIdx.x*256 + threadIdx.x;
  if (i < 256*384) w0b[i] = f2bf(w0[i]);
  int j = i - 256*384;
  if (j >= 0 && j < 256*256) w1b[j] = f2bf(w1[j]);
}

// ------------- GEMM: Y[M][256] = A[M][KDIM] @ W[256][KDIM]^T + bias ----------
// BM=128, BN=256 (full), BK=64. 4 waves, wave w owns cols [w*64, w*64+64).
// AFUSE (gemm0): A is NOT materialized — staged on the fly:
//   k <  128: A[m][k]    = f2bf(ofeat[m][k])
//   k >= 128: A[m][k]    = f2bf(fma(w2,s2, fma(w1,s1, mul(w0,s0))))   (interp)
// with per-row kw/ki preloaded to LDS (exact same expressions as the old
// interp kernel -> bit-identical A bits). BNRELU (gemm1): BN0 scale/shift
// computed in-kernel from gemm0 stats, A' = relu(A*sc+sh) during staging.
// Epilogue: bf16 store + per-channel sum/sumsq atomics for BN stats.
template<int KDIM, bool BNRELU, bool AFUSE>
__global__ __launch_bounds__(256) void gemm_kernel(
    const unsigned short* __restrict__ A,
    const unsigned short* __restrict__ W,
    const float* __restrict__ bias,
    const float* __restrict__ s0sum,
    const float* __restrict__ s0sq,
    const float* __restrict__ bng,
    const float* __restrict__ bnbt,
    const float* __restrict__ kwg,
    const int*   __restrict__ kig,
    const float* __restrict__ sfeat,
    const float* __restrict__ ofeat,
    unsigned short* __restrict__ Y,
    float* __restrict__ osum,
    float* __restrict__ osq)
{
  __shared__ unsigned short As[128*64];   // 16 KB, XOR-swizzled 16B chunks
  __shared__ unsigned short Bs[256*64];   // 32 KB
  __shared__ float lsc[256], lsh[256];    // BNRELU only
  __shared__ float lkw[128][3];           // AFUSE only
  __shared__ int   lki[128][3];
  const int tid  = threadIdx.x;
  const int lane = tid & 63;
  const int wave = tid >> 6;
  const size_t mbase = (size_t)blockIdx.x * 128;
  if constexpr (BNRELU){
    float mean = s0sum[tid] * (1.0f/65536.0f);
    float var  = s0sq[tid] * (1.0f/65536.0f) - mean*mean;
    float s = bng[tid] / sqrtf(var + 1e-5f);
    lsc[tid] = s;
    lsh[tid] = __fmaf_rn(-mean, s, bnbt[tid]);
  }
  if constexpr (AFUSE){
    float* lkwf = &lkw[0][0];
    int*   lkif = &lki[0][0];
    for (int t = tid; t < 384; t += 256){
      lkwf[t] = kwg[mbase*3 + t];
      lkif[t] = kig[mbase*3 + t];
    }
  }
  f32x4 acc[8][4];
  #pragma unroll
  for (int m2 = 0; m2 < 8; ++m2)
    #pragma unroll
    for (int n2 = 0; n2 < 4; ++n2) acc[m2][n2] = f32x4{0.f,0.f,0.f,0.f};
  __syncthreads();

  for (int k0 = 0; k0 < KDIM; k0 += 64){
    if (k0) __syncthreads();
    // stage A: 128 rows x 8 chunks(16B) = 1024 chunks, 4/thread
    #pragma unroll
    for (int i = 0; i < 4; ++i){
      int cid = tid + 256*i;
      int row = cid >> 3, c8 = cid & 7;
      short8 v;
      if constexpr (AFUSE){
        const int m = (int)mbase + row;
        const int k = k0 + c8*8;
        float vals[8];
        if (k < COn){
          const float4* p = reinterpret_cast<const float4*>(ofeat + (size_t)m*COn + k);
          float4 u0 = p[0], u1 = p[1];
          vals[0]=u0.x; vals[1]=u0.y; vals[2]=u0.z; vals[3]=u0.w;
          vals[4]=u1.x; vals[5]=u1.y; vals[6]=u1.z; vals[7]=u1.w;
        } else {
          const int cc = k - COn;
          const int bb = m >> 14;
          const float* sb = sfeat + (size_t)bb*Sn*CSn;
          const float w0v = lkw[row][0], w1v = lkw[row][1], w2v = lkw[row][2];
          const int   i0  = lki[row][0], i1  = lki[row][1], i2  = lki[row][2];
          const float4* p0 = reinterpret_cast<const float4*>(sb + (size_t)i0*CSn + cc);
          const float4* p1 = reinterpret_cast<const float4*>(sb + (size_t)i1*CSn + cc);
          const float4* p2 = reinterpret_cast<const float4*>(sb + (size_t)i2*CSn + cc);
          float4 a0 = p0[0], a1 = p0[1];
          float4 b0v = p1[0], b1v = p1[1];
          float4 c0v = p2[0], c1v = p2[1];
          float s0[8] = {a0.x,a0.y,a0.z,a0.w,a1.x,a1.y,a1.z,a1.w};
          float s1[8] = {b0v.x,b0v.y,b0v.z,b0v.w,b1v.x,b1v.y,b1v.z,b1v.w};
          float s2[8] = {c0v.x,c0v.y,c0v.z,c0v.w,c1v.x,c1v.y,c1v.z,c1v.w};
          #pragma unroll
          for (int j = 0; j < 8; ++j)
            vals[j] = __fmaf_rn(w2v, s2[j], __fmaf_rn(w1v, s1[j], __fmul_rn(w0v, s0[j])));
        }
        #pragma unroll
        for (int j = 0; j < 8; ++j) v[j] = (short)f2bf(vals[j]);
      } else {
        v = *reinterpret_cast<const short8*>(A + (mbase+row)*KDIM + k0 + c8*8);
        if constexpr (BNRELU){
          #pragma unroll
          for (int j = 0; j < 8; ++j){
            int kc = k0 + c8*8 + j;
            float f = bf2f((unsigned short)v[j]);
            f = fmaxf(__fmaf_rn(f, lsc[kc], lsh[kc]), 0.0f);
            v[j] = (short)f2bf(f);
          }
        }
      }
      *reinterpret_cast<short8*>(reinterpret_cast<char*>(As) + row*128 + ((c8 ^ (row&7)) << 4)) = v;
    }
    // stage B (weights): 256 rows x 8 chunks = 2048 chunks, 8/thread
    #pragma unroll
    for (int i = 0; i < 8; ++i){
      int cid = tid + 256*i;
      int row = cid >> 3, c8 = cid & 7;
      short8 v = *reinterpret_cast<const short8*>(W + (size_t)row*KDIM + k0 + c8*8);
      *reinterpret_cast<short8*>(reinterpret_cast<char*>(Bs) + row*128 + ((c8 ^ (row&7)) << 4)) = v;
    }
    __syncthreads();
    #pragma unroll
    for (int kk = 0; kk < 2; ++kk){
      short8 af[8], bv[4];
      #pragma unroll
      for (int m2 = 0; m2 < 8; ++m2){
        int row = m2*16 + (lane & 15);
        int c8  = kk*4 + (lane >> 4);
        af[m2] = *reinterpret_cast<const short8*>(reinterpret_cast<char*>(As) + row*128 + ((c8 ^ (row&7)) << 4));
      }
      #pragma unroll
      for (int n2 = 0; n2 < 4; ++n2){
        int row = wave*64 + n2*16 + (lane & 15);
        int c8  = kk*4 + (lane >> 4);
        bv[n2] = *reinterpret_cast<const short8*>(reinterpret_cast<char*>(Bs) + row*128 + ((c8 ^ (row&7)) << 4));
      }
      #pragma unroll
      for (int m2 = 0; m2 < 8; ++m2)
        #pragma unroll
        for (int n2 = 0; n2 < 4; ++n2)
          acc[m2][n2] = __builtin_amdgcn_mfma_f32_16x16x32_bf16(af[m2], bv[n2], acc[m2][n2], 0, 0, 0);
    }
  }

  // epilogue: C/D layout col = lane&15, row = (lane>>4)*4 + j  [m89-verified]
  const int colg0 = wave*64;
  float spart[4] = {0,0,0,0}, qpart[4] = {0,0,0,0};
  #pragma unroll
  for (int m2 = 0; m2 < 8; ++m2){
    #pragma unroll
    for (int n2 = 0; n2 < 4; ++n2){
      const int gc  = colg0 + n2*16 + (lane & 15);
      const float bvv = bias[gc];
      #pragma unroll
      for (int j = 0; j < 4; ++j){
        float yv = acc[m2][n2][j] + bvv;
        size_t gr = mbase + m2*16 + (lane>>4)*4 + j;
        Y[gr*256 + gc] = f2bf(yv);
        spart[n2] += yv;
        qpart[n2] = __fmaf_rn(yv, yv, qpart[n2]);
      }
    }
  }
  #pragma unroll
  for (int n2 = 0; n2 < 4; ++n2){
    float s = spart[n2], q = qpart[n2];
    s += __shfl_xor(s, 16); q += __shfl_xor(q, 16);
    s += __shfl_xor(s, 32); q += __shfl_xor(q, 32);
    if (lane < 16){
      int gc = colg0 + n2*16 + lane;
      atomicAdd(&osum[gc], s);
      atomicAdd(&osq[gc], q);
    }
  }
}

// ------------- final BN1 + ReLU -> fp32 out (BN finalize folded in) -------------
__global__ __launch_bounds__(256) void apply_kernel(
    const unsigned short* __restrict__ y,
    const float* __restrict__ s1sum, const float* __restrict__ s1sq,
    const float* __restrict__ g, const float* __restrict__ bt,
    float* __restrict__ out)
{
  __shared__ float ssc[256], ssh[256];
  {
    int c = threadIdx.x;
    float mean = s1sum[c] * (1.0f/65536.0f);
    float var  = s1sq[c] * (1.0f/65536.0f) - mean*mean;
    float s = g[c] / sqrtf(var + 1e-5f);
    ssc[c] = s;
    ssh[c] = __fmaf_rn(-mean, s, bt[c]);
  }
  __syncthreads();
  const int t = blockIdx.x*256 + threadIdx.x;
  const size_t base = (size_t)t * 8;
  const int c0 = (int)(base & 255);
  short8 v = *reinterpret_cast<const short8*>(y + base);
  float r[8];
  #pragma unroll
  for (int j = 0; j < 8; ++j){
    float f = bf2f((unsigned short)v[j]);
    f = __fmaf_rn(f, ssc[c0+j], ssh[c0+j]);
    r[j] = fmaxf(f, 0.0f);
  }
  float4 o0, o1;
  o0.x=r[0]; o0.y=r[1]; o0.z=r[2]; o0.w=r[3];
  o1.x=r[4]; o1.y=r[5]; o1.z=r[6]; o1.w=r[7];
  *reinterpret_cast<float4*>(out + base)     = o0;
  *reinterpret_cast<float4*>(out + base + 4) = o1;
}

// ---------------- workspace layout ----------------
constexpr size_t WS_STATS = 0;                                  // 4*256 f32
constexpr size_t WS_W0B   = 8192;                               // 98304 bf16
constexpr size_t WS_W1B   = WS_W0B + 196608;                    // 65536 bf16
constexpr size_t WS_KW    = WS_W1B + 131072;                    // M*3 f32
constexpr size_t WS_KI    = WS_KW + 786432;                     // M*3 i32
constexpr size_t WS_BIG   = 4194304;                            // big region
constexpr size_t WS_Y0    = WS_BIG + (size_t)MTOT*CINn*2;       // M*256 bf16
// PD/PI (6.3 MB each) live at the start of the big region; they are dead
// after knnmerge. Y1 reuses the same region (written by gemm1, later).
constexpr size_t WS_PD    = WS_BIG;
constexpr size_t WS_PI    = WS_BIG + (size_t)8*3*MTOT*4;

extern "C" void kernel_launch(void* const* d_in, const int* in_sizes, int n_in,
                              void* d_out, int out_size, void* d_ws, size_t ws_size,
                              hipStream_t stream)
{
  const float* sxyz  = (const float*)d_in[0];
  const float* sfeat = (const float*)d_in[1];
  const float* oxyz  = (const float*)d_in[2];
  const float* ofeat = (const float*)d_in[3];
  const float* w0    = (const float*)d_in[4];
  const float* b0    = (const float*)d_in[5];
  const float* g0    = (const float*)d_in[6];
  const float* bt0   = (const float*)d_in[7];
  const float* w1    = (const float*)d_in[8];
  const float* b1    = (const float*)d_in[9];
  const float* g1    = (const float*)d_in[10];
  const float* bt1   = (const float*)d_in[11];
  // d_in[12] = k (always 3, hard-coded)

  char* ws = (char*)d_ws;
  float* stats  = (float*)(ws + WS_STATS);   // sum0,ssq0,sum1,ssq1
  unsigned short* w0b = (unsigned short*)(ws + WS_W0B);
  unsigned short* w1b = (unsigned short*)(ws + WS_W1B);
  float* kw = (float*)(ws + WS_KW);
  int*   ki = (int*)(ws + WS_KI);
  float* PD = (float*)(ws + WS_PD);
  int*   PI = (int*)(ws + WS_PI);
  unsigned short* Y0 = (unsigned short*)(ws + WS_Y0);
  unsigned short* Y1 = (unsigned short*)(ws + WS_BIG);   // reuse (PD/PI dead)

  hipMemsetAsync(stats, 0, 4*256*sizeof(float), stream);
  cvtw_kernel<<<640, 256, 0, stream>>>(w0, w1, w0b, w1b);
  knn_kernel<<<4096, 128, 0, stream>>>(sxyz, oxyz, PD, PI);
  knnmerge_kernel<<<MTOT/256, 256, 0, stream>>>(PD, PI, kw, ki);
  gemm_kernel<CINn, false, true><<<MTOT/128, 256, 0, stream>>>(
      nullptr, w0b, b0, nullptr, nullptr, nullptr, nullptr,
      kw, ki, sfeat, ofeat, Y0, stats, stats + 256);
  gemm_kernel<256, true, false><<<MTOT/128, 256, 0, stream>>>(
      Y0, w1b, b1, stats, stats + 256, g0, bt0,
      nullptr, nullptr, nullptr, nullptr, Y1, stats + 512, stats + 768);
  apply_kernel<<<(MTOT*256)/(256*8), 256, 0, stream>>>(
      Y1, stats + 512, stats + 768, g1, bt1, (float*)d_out);
}